// Round 4
// baseline (14113.943 us; speedup 1.0000x reference)
//
#include <hip/hip_runtime.h>
#include <cmath>

#define B_ 128
#define T_ 480
#define BT_ 61440

// output layout (fp32 elements)
#define OUT_SPK1 512
#define OUT_SPK2 3932672
#define OUT_SPK3 11796992

__device__ __forceinline__ double softplus_d(double x) {
    return (x > 0.0) ? (x + log1p(exp(-x))) : log1p(exp(x));
}
__device__ __forceinline__ double sigmoid_d(double x) {
    return 1.0 / (1.0 + exp(-x));
}

// ---------------------------------------------------------------------------
// Kernel 1: conv1 (61440x64 @ 64x64) + bn1 -> xbuf (f64). Also zeros zrow.
// ---------------------------------------------------------------------------
__global__ __launch_bounds__(256)
void conv1_bn(const float* __restrict__ x, const float* __restrict__ w1,
              const float* __restrict__ sc, const float* __restrict__ bi,
              const float* __restrict__ mn, const float* __restrict__ vr,
              double* __restrict__ xo, float* __restrict__ zrow)
{
    __shared__ float wl[64 * 64];
    __shared__ float xl[4 * 64];
    int tid = threadIdx.x;
    if (blockIdx.x == 0 && tid < 128) zrow[tid] = 0.0f;   // zero row for conv3 OOB
#pragma unroll
    for (int i = 0; i < 16; i++) wl[tid + 256 * i] = w1[tid + 256 * i];
    int row0 = blockIdx.x * 4;
    xl[tid] = x[(size_t)row0 * 64 + tid];
    __syncthreads();
    int o = tid & 63, r = tid >> 6;
    double acc = 0.0;
#pragma unroll
    for (int w = 0; w < 64; w++)
        acc = fma((double)xl[r * 64 + w], (double)wl[w * 64 + o], acc);
    double y = (acc - (double)mn[o]) * (1.0 / sqrt((double)vr[o] + 1e-5)) * (double)sc[o]
             + (double)bi[o];
    xo[(size_t)(row0 + r) * 64 + o] = y;
}

// ---------------------------------------------------------------------------
// Kernel 2/4: HLIF scan over T per (b,c).
// ---------------------------------------------------------------------------
__global__ void hlif(const double* __restrict__ xin, float* __restrict__ spk,
                     const float* __restrict__ vth_raw, const float* __restrict__ dec_raw,
                     int C)
{
    int idx = blockIdx.x * blockDim.x + threadIdx.x;
    int b = idx / C, c = idx - b * C;
    double vth = softplus_d((double)vth_raw[c]) + 0.5;
    double dec = sigmoid_d((double)dec_raw[c] + 2.0);
    dec = fmin(fmax(dec, 0.0), 0.99);
    const double* xp = xin + (size_t)b * T_ * C + c;
    float* sp = spk + (size_t)b * T_ * C + c;
    double v = 0.0;
    for (int t = 0; t < T_; t += 8) {
        double xv[8];
#pragma unroll
        for (int u = 0; u < 8; u++) xv[u] = xp[(size_t)(t + u) * C];
#pragma unroll
        for (int u = 0; u < 8; u++) {
            v = v * dec + xv[u];
            double s = (v - vth > 0.0) ? 1.0 : 0.0;
            v -= s * vth;
            sp[(size_t)(t + u) * C] = (float)s;
        }
    }
}

// ---------------------------------------------------------------------------
// XCD-locality block swizzle for the 128b x 30tt conv grids: all 30 tt-tiles
// of a batch b land on the same XCD (blockIdx%8 fixed per b) so spk + weights
// stay L2-resident per XCD. Bijective for grid 3840.
// ---------------------------------------------------------------------------
__device__ __forceinline__ void swz_b_tt(int j, int& bb, int& tt) {
    int xcd = j & 7, slot = j >> 3;       // slot in [0,480)
    bb = xcd + 8 * (slot / 30);           // 16 b's per XCD
    tt = slot % 30;
}

// ---------------------------------------------------------------------------
// Kernel 3: conv2 (K=32, dil=4, pad 62, Cin=64, Cout=128) + bn2 -> xbuf (f64)
// Hybrid precision: per-k 64-term partial in f32 (fmac, no cvt), k-sum in f64.
// ---------------------------------------------------------------------------
__global__ __launch_bounds__(256)
void conv2_bn(const float* __restrict__ spk1, const float* __restrict__ w2,
              const float* __restrict__ sc, const float* __restrict__ bi,
              const float* __restrict__ mn, const float* __restrict__ vr,
              double* __restrict__ xo)
{
    __shared__ float S[140 * 64];   // rows t0-62 .. t0+15+62
    int tid = threadIdx.x;
    int bb, tt;
    swz_b_tt(blockIdx.x, bb, tt);
    int t0 = tt * 16;
    const float* sb = spk1 + (size_t)bb * T_ * 64;
    for (int i = tid; i < 140 * 64; i += 256) {
        int rr = i >> 6, cc = i & 63;
        int t = t0 - 62 + rr;
        S[i] = (t >= 0 && t < T_) ? sb[(size_t)t * 64 + cc] : 0.0f;
    }
    __syncthreads();
    int o = tid & 127, th = tid >> 7;
    double acc[8];
#pragma unroll
    for (int j = 0; j < 8; j++) acc[j] = 0.0;

    for (int k = 0; k < 32; k++) {
        int rbase = th * 8 + 4 * k;   // row for (j) = rbase + j
        const float* wp = w2 + (size_t)k * 64 * 128 + o;
        float p[8];
#pragma unroll
        for (int j = 0; j < 8; j++) p[j] = 0.0f;
        for (int cc = 0; cc < 64; cc += 4) {
            float4 sv[8];
#pragma unroll
            for (int j = 0; j < 8; j++)
                sv[j] = *(const float4*)&S[(rbase + j) * 64 + cc];
#pragma unroll
            for (int q = 0; q < 4; q++) {
                float w = wp[(size_t)(cc + q) * 128];
#pragma unroll
                for (int j = 0; j < 8; j++)
                    p[j] = fmaf(((const float*)&sv[j])[q], w, p[j]);
            }
        }
#pragma unroll
        for (int j = 0; j < 8; j++) acc[j] += (double)p[j];
    }
    double m = (double)mn[o], rs = 1.0 / sqrt((double)vr[o] + 1e-5);
    double s_ = (double)sc[o], b_ = (double)bi[o];
    double* xop = xo + ((size_t)bb * T_ + t0 + th * 8) * 128 + o;
#pragma unroll
    for (int j = 0; j < 8; j++) xop[(size_t)j * 128] = (acc[j] - m) * rs * s_ + b_;
}

// ---------------------------------------------------------------------------
// Kernel 5: conv3 (K=32, dil=12, pad 186, Cin=128, Cout=128) + bn3 -> xbuf
// Hybrid precision + XCD swizzle + depth-1 register double-buffer prefetch.
// FMA order per accumulator identical to round-3 kernel (bitwise-same result).
// ---------------------------------------------------------------------------
__global__ __launch_bounds__(256, 4)
void conv3_bn(const float* __restrict__ spk2, const float* __restrict__ w3,
              const float* __restrict__ sc, const float* __restrict__ bi,
              const float* __restrict__ mn, const float* __restrict__ vr,
              const float* __restrict__ zrow, double* __restrict__ xo)
{
    int tid = threadIdx.x;
    int bb, tt;
    swz_b_tt(blockIdx.x, bb, tt);
    int t0 = tt * 16;
    const float* sb = spk2 + (size_t)bb * T_ * 128;
    int o = tid & 127, th = tid >> 7;
    double acc[8];
#pragma unroll
    for (int j = 0; j < 8; j++) acc[j] = 0.0;

    for (int k = 0; k < 32; k++) {
        int tb = t0 + th * 8 + 12 * k - 186;
        const float* rp[8];
#pragma unroll
        for (int j = 0; j < 8; j++) {
            int t = tb + j;
            rp[j] = (t >= 0 && t < T_) ? (sb + (size_t)t * 128) : zrow;
        }
        const float* wp = w3 + (size_t)k * 128 * 128 + o;
        float p[8];
#pragma unroll
        for (int j = 0; j < 8; j++) p[j] = 0.0f;

        float4 cur[8];
#pragma unroll
        for (int j = 0; j < 8; j++) cur[j] = *(const float4*)(rp[j]);

#pragma unroll 2
        for (int cc = 0; cc < 128; cc += 4) {
            float4 nxt[8];
            if (cc + 4 < 128) {
#pragma unroll
                for (int j = 0; j < 8; j++) nxt[j] = *(const float4*)(rp[j] + cc + 4);
            }
            float w0 = wp[(size_t)(cc + 0) * 128];
            float w1 = wp[(size_t)(cc + 1) * 128];
            float w2_ = wp[(size_t)(cc + 2) * 128];
            float w3_ = wp[(size_t)(cc + 3) * 128];
#pragma unroll
            for (int j = 0; j < 8; j++) {
                p[j] = fmaf(cur[j].x, w0, p[j]);
                p[j] = fmaf(cur[j].y, w1, p[j]);
                p[j] = fmaf(cur[j].z, w2_, p[j]);
                p[j] = fmaf(cur[j].w, w3_, p[j]);
            }
            if (cc + 4 < 128) {
#pragma unroll
                for (int j = 0; j < 8; j++) cur[j] = nxt[j];
            }
        }
#pragma unroll
        for (int j = 0; j < 8; j++) acc[j] += (double)p[j];
    }
    double m = (double)mn[o], rs = 1.0 / sqrt((double)vr[o] + 1e-5);
    double s_ = (double)sc[o], b_ = (double)bi[o];
    double* xop = xo + ((size_t)bb * T_ + t0 + th * 8) * 128 + o;
#pragma unroll
    for (int j = 0; j < 8; j++) xop[(size_t)j * 128] = (acc[j] - m) * rs * s_ + b_;
}

// ---------------------------------------------------------------------------
// Kernel 6: ALIF scan per (b,c), C=128.
// ---------------------------------------------------------------------------
__global__ void alif(const double* __restrict__ xin, float* __restrict__ spk)
{
    int idx = blockIdx.x * blockDim.x + threadIdx.x;
    int b = idx >> 7, c = idx & 127;
    const double* xp = xin + (size_t)b * T_ * 128 + c;
    float* sp = spk + (size_t)b * T_ * 128 + c;
    double v = 0.0, th = 0.0, ps = 0.0;
    const double dd = 0.9, adp = 0.9, beta = 1.8;
    for (int t = 0; t < T_; t += 8) {
        double xv[8];
#pragma unroll
        for (int u = 0; u < 8; u++) xv[u] = xp[(size_t)(t + u) * 128];
#pragma unroll
        for (int u = 0; u < 8; u++) {
            th = th * adp + ps * beta;
            v = v * dd + xv[u];
            double vth = 0.5 + th;
            double s = (v - vth > 0.0) ? 1.0 : 0.0;
            v -= s * vth;
            ps = s;
            sp[(size_t)(t + u) * 128] = (float)s;
        }
    }
}

// ---------------------------------------------------------------------------
// Kernel 7: readout — dense + LI scan + dp + attention + logits. 1 block per b.
// ---------------------------------------------------------------------------
__global__ __launch_bounds__(256)
void readout(const float* __restrict__ spk3, const float* __restrict__ dw,
             const float* __restrict__ db, const float* __restrict__ a1w,
             const float* __restrict__ a1b, const float* __restrict__ a2w,
             const float* __restrict__ a2b, float* __restrict__ out)
{
    __shared__ double dl[480 * 4];
    __shared__ double dp[20 * 4];
    __shared__ double zl[20];
    __shared__ double red[1];
    int b = blockIdx.x, tid = threadIdx.x;
    const float* sp = spk3 + (size_t)b * T_ * 128;

    // dense: (480,128) @ (128,4) + bias
    for (int i = tid; i < 1920; i += 256) {
        int t = i >> 2, j = i & 3;
        const float* row = sp + (size_t)t * 128;
        double acc = 0.0;
        for (int c = 0; c < 128; c++)
            acc = fma((double)row[c], (double)dw[c * 4 + j], acc);
        dl[i] = acc + (double)db[j];
    }
    __syncthreads();
    // LI scan: v = v*0.9 + x*(1-0.9)
    if (tid < 4) {
        const double dec = 0.9, om = 1.0 - 0.9;
        double v = 0.0;
        for (int t = 0; t < T_; t++) {
            v = v * dec + dl[t * 4 + tid] * om;
            dl[t * 4 + tid] = v;
        }
    }
    __syncthreads();
    // dp = mean(last 12) - mean(first 12) per (g, j)
    if (tid < 80) {
        int g = tid >> 2, j = tid & 3;
        double s1 = 0.0, s2 = 0.0;
        for (int u = 0; u < 12; u++) {
            s1 += dl[(g * 24 + u) * 4 + j];
            s2 += dl[(g * 24 + 12 + u) * 4 + j];
        }
        dp[g * 4 + j] = s2 / 12.0 - s1 / 12.0;
    }
    __syncthreads();
    // z[g] = relu(dp@a1w + a1b) @ a2w + a2b
    if (tid < 20) {
        int g = tid;
        double z = (double)a2b[0];
        for (int i = 0; i < 8; i++) {
            double h = (double)a1b[i];
            for (int j = 0; j < 4; j++)
                h = fma(dp[g * 4 + j], (double)a1w[j * 8 + i], h);
            h = fmax(h, 0.0);
            z = fma(h, (double)a2w[i], z);
        }
        zl[g] = z;
    }
    __syncthreads();
    if (tid == 0) {
        double m = zl[0];
        for (int g = 1; g < 20; g++) m = fmax(m, zl[g]);
        double s = 0.0;
        for (int g = 0; g < 20; g++) { zl[g] = exp(zl[g] - m); s += zl[g]; }
        red[0] = s;
    }
    __syncthreads();
    if (tid < 4) {
        double s = red[0];
        double acc = 0.0;
        for (int g = 0; g < 20; g++) acc += dp[g * 4 + tid] * (zl[g] / s);
        out[b * 4 + tid] = (float)acc;
    }
}

// ---------------------------------------------------------------------------
extern "C" void kernel_launch(void* const* d_in, const int* in_sizes, int n_in,
                              void* d_out, int out_size, void* d_ws, size_t ws_size,
                              hipStream_t stream)
{
    const float* x     = (const float*)d_in[0];
    const float* w1    = (const float*)d_in[1];
    const float* bn1s  = (const float*)d_in[2];
    const float* bn1b  = (const float*)d_in[3];
    const float* bn1m  = (const float*)d_in[4];
    const float* bn1v  = (const float*)d_in[5];
    const float* vth1  = (const float*)d_in[6];
    const float* dec1  = (const float*)d_in[7];
    const float* w2    = (const float*)d_in[8];
    const float* bn2s  = (const float*)d_in[9];
    const float* bn2b  = (const float*)d_in[10];
    const float* bn2m  = (const float*)d_in[11];
    const float* bn2v  = (const float*)d_in[12];
    const float* vth2  = (const float*)d_in[13];
    const float* dec2  = (const float*)d_in[14];
    const float* w3    = (const float*)d_in[15];
    const float* bn3s  = (const float*)d_in[16];
    const float* bn3b  = (const float*)d_in[17];
    const float* bn3m  = (const float*)d_in[18];
    const float* bn3v  = (const float*)d_in[19];
    const float* dw    = (const float*)d_in[20];
    const float* db    = (const float*)d_in[21];
    const float* a1w   = (const float*)d_in[22];
    const float* a1b   = (const float*)d_in[23];
    const float* a2w   = (const float*)d_in[24];
    const float* a2b   = (const float*)d_in[25];

    float* out = (float*)d_out;
    double* xbuf = (double*)d_ws;                         // 61440*128 doubles = 62.9 MB
    float* zrow = (float*)(xbuf + (size_t)BT_ * 128);     // 128 zero floats for conv3 OOB

    // Stage 1
    conv1_bn<<<BT_ / 4, 256, 0, stream>>>(x, w1, bn1s, bn1b, bn1m, bn1v, xbuf, zrow);
    hlif<<<(B_ * 64) / 256, 256, 0, stream>>>(xbuf, out + OUT_SPK1, vth1, dec1, 64);
    // Stage 2
    conv2_bn<<<B_ * 30, 256, 0, stream>>>(out + OUT_SPK1, w2, bn2s, bn2b, bn2m, bn2v, xbuf);
    hlif<<<(B_ * 128) / 256, 256, 0, stream>>>(xbuf, out + OUT_SPK2, vth2, dec2, 128);
    // Stage 3
    conv3_bn<<<B_ * 30, 256, 0, stream>>>(out + OUT_SPK2, w3, bn3s, bn3b, bn3m, bn3v, zrow, xbuf);
    alif<<<(B_ * 128) / 256, 256, 0, stream>>>(xbuf, out + OUT_SPK3);
    // Readout
    readout<<<B_, 256, 0, stream>>>(out + OUT_SPK3, dw, db, a1w, a1b, a2w, a2b, out);
}

// Round 5
// 4602.555 us; speedup vs baseline: 3.0665x; 3.0665x over previous
//
#include <hip/hip_runtime.h>
#include <cmath>

#define B_ 128
#define T_ 480
#define BT_ 61440

// output layout (fp32 elements)
#define OUT_SPK1 512
#define OUT_SPK2 3932672
#define OUT_SPK3 11796992

__device__ __forceinline__ double softplus_d(double x) {
    return (x > 0.0) ? (x + log1p(exp(-x))) : log1p(exp(x));
}
__device__ __forceinline__ double sigmoid_d(double x) {
    return 1.0 / (1.0 + exp(-x));
}

// ---------------------------------------------------------------------------
// Kernel 1: conv1 (61440x64 @ 64x64) + bn1 -> xbuf (f64). Also zeros zrow.
// ---------------------------------------------------------------------------
__global__ __launch_bounds__(256)
void conv1_bn(const float* __restrict__ x, const float* __restrict__ w1,
              const float* __restrict__ sc, const float* __restrict__ bi,
              const float* __restrict__ mn, const float* __restrict__ vr,
              double* __restrict__ xo, float* __restrict__ zrow)
{
    __shared__ float wl[64 * 64];
    __shared__ float xl[4 * 64];
    int tid = threadIdx.x;
    if (blockIdx.x == 0 && tid < 128) zrow[tid] = 0.0f;   // zero row for conv3 OOB
#pragma unroll
    for (int i = 0; i < 16; i++) wl[tid + 256 * i] = w1[tid + 256 * i];
    int row0 = blockIdx.x * 4;
    xl[tid] = x[(size_t)row0 * 64 + tid];
    __syncthreads();
    int o = tid & 63, r = tid >> 6;
    double acc = 0.0;
#pragma unroll
    for (int w = 0; w < 64; w++)
        acc = fma((double)xl[r * 64 + w], (double)wl[w * 64 + o], acc);
    double y = (acc - (double)mn[o]) * (1.0 / sqrt((double)vr[o] + 1e-5)) * (double)sc[o]
             + (double)bi[o];
    xo[(size_t)(row0 + r) * 64 + o] = y;
}

// ---------------------------------------------------------------------------
// Kernel 2/4: HLIF scan over T per (b,c).
// ---------------------------------------------------------------------------
__global__ void hlif(const double* __restrict__ xin, float* __restrict__ spk,
                     const float* __restrict__ vth_raw, const float* __restrict__ dec_raw,
                     int C)
{
    int idx = blockIdx.x * blockDim.x + threadIdx.x;
    int b = idx / C, c = idx - b * C;
    double vth = softplus_d((double)vth_raw[c]) + 0.5;
    double dec = sigmoid_d((double)dec_raw[c] + 2.0);
    dec = fmin(fmax(dec, 0.0), 0.99);
    const double* xp = xin + (size_t)b * T_ * C + c;
    float* sp = spk + (size_t)b * T_ * C + c;
    double v = 0.0;
    for (int t = 0; t < T_; t += 8) {
        double xv[8];
#pragma unroll
        for (int u = 0; u < 8; u++) xv[u] = xp[(size_t)(t + u) * C];
#pragma unroll
        for (int u = 0; u < 8; u++) {
            v = v * dec + xv[u];
            double s = (v - vth > 0.0) ? 1.0 : 0.0;
            v -= s * vth;
            sp[(size_t)(t + u) * C] = (float)s;
        }
    }
}

// ---------------------------------------------------------------------------
// XCD-locality block swizzle for the 128b x 30tt conv grids: all 30 tt-tiles
// of a batch b land on the same XCD (blockIdx%8 fixed per b) so spk + weights
// stay L2-resident per XCD. Bijective for grid 3840.
// ---------------------------------------------------------------------------
__device__ __forceinline__ void swz_b_tt(int j, int& bb, int& tt) {
    int xcd = j & 7, slot = j >> 3;       // slot in [0,480)
    bb = xcd + 8 * (slot / 30);           // 16 b's per XCD
    tt = slot % 30;
}

// ---------------------------------------------------------------------------
// Kernel 3: conv2 (K=32, dil=4, pad 62, Cin=64, Cout=128) + bn2 -> xbuf (f64)
// Hybrid precision: per-k 64-term partial in f32 (fmac, no cvt), k-sum in f64.
// ---------------------------------------------------------------------------
__global__ __launch_bounds__(256)
void conv2_bn(const float* __restrict__ spk1, const float* __restrict__ w2,
              const float* __restrict__ sc, const float* __restrict__ bi,
              const float* __restrict__ mn, const float* __restrict__ vr,
              double* __restrict__ xo)
{
    __shared__ float S[140 * 64];   // rows t0-62 .. t0+15+62
    int tid = threadIdx.x;
    int bb, tt;
    swz_b_tt(blockIdx.x, bb, tt);
    int t0 = tt * 16;
    const float* sb = spk1 + (size_t)bb * T_ * 64;
    for (int i = tid; i < 140 * 64; i += 256) {
        int rr = i >> 6, cc = i & 63;
        int t = t0 - 62 + rr;
        S[i] = (t >= 0 && t < T_) ? sb[(size_t)t * 64 + cc] : 0.0f;
    }
    __syncthreads();
    int o = tid & 127, th = tid >> 7;
    double acc[8];
#pragma unroll
    for (int j = 0; j < 8; j++) acc[j] = 0.0;

    for (int k = 0; k < 32; k++) {
        int rbase = th * 8 + 4 * k;   // row for (j) = rbase + j
        const float* wp = w2 + (size_t)k * 64 * 128 + o;
        float p[8];
#pragma unroll
        for (int j = 0; j < 8; j++) p[j] = 0.0f;
        for (int cc = 0; cc < 64; cc += 4) {
            float4 sv[8];
#pragma unroll
            for (int j = 0; j < 8; j++)
                sv[j] = *(const float4*)&S[(rbase + j) * 64 + cc];
#pragma unroll
            for (int q = 0; q < 4; q++) {
                float w = wp[(size_t)(cc + q) * 128];
#pragma unroll
                for (int j = 0; j < 8; j++)
                    p[j] = fmaf(((const float*)&sv[j])[q], w, p[j]);
            }
        }
#pragma unroll
        for (int j = 0; j < 8; j++) acc[j] += (double)p[j];
    }
    double m = (double)mn[o], rs = 1.0 / sqrt((double)vr[o] + 1e-5);
    double s_ = (double)sc[o], b_ = (double)bi[o];
    double* xop = xo + ((size_t)bb * T_ + t0 + th * 8) * 128 + o;
#pragma unroll
    for (int j = 0; j < 8; j++) xop[(size_t)j * 128] = (acc[j] - m) * rs * s_ + b_;
}

// ---------------------------------------------------------------------------
// Kernel 5: conv3 (K=32, dil=12, pad 186, Cin=128, Cout=128) + bn3 -> xbuf
// Round-3 body (VGPR ~52, no spill) + XCD swizzle only.
// ---------------------------------------------------------------------------
__global__ __launch_bounds__(256)
void conv3_bn(const float* __restrict__ spk2, const float* __restrict__ w3,
              const float* __restrict__ sc, const float* __restrict__ bi,
              const float* __restrict__ mn, const float* __restrict__ vr,
              const float* __restrict__ zrow, double* __restrict__ xo)
{
    int tid = threadIdx.x;
    int bb, tt;
    swz_b_tt(blockIdx.x, bb, tt);
    int t0 = tt * 16;
    const float* sb = spk2 + (size_t)bb * T_ * 128;
    int o = tid & 127, th = tid >> 7;
    double acc[8];
#pragma unroll
    for (int j = 0; j < 8; j++) acc[j] = 0.0;

    for (int k = 0; k < 32; k++) {
        int tb = t0 + th * 8 + 12 * k - 186;
        const float* rp[8];
#pragma unroll
        for (int j = 0; j < 8; j++) {
            int t = tb + j;
            rp[j] = (t >= 0 && t < T_) ? (sb + (size_t)t * 128) : zrow;
        }
        const float* wp = w3 + (size_t)k * 128 * 128 + o;
        float p[8];
#pragma unroll
        for (int j = 0; j < 8; j++) p[j] = 0.0f;
        for (int cc = 0; cc < 128; cc += 4) {
            float4 sv[8];
#pragma unroll
            for (int j = 0; j < 8; j++)
                sv[j] = *(const float4*)(rp[j] + cc);
#pragma unroll
            for (int q = 0; q < 4; q++) {
                float w = wp[(size_t)(cc + q) * 128];
#pragma unroll
                for (int j = 0; j < 8; j++)
                    p[j] = fmaf(((const float*)&sv[j])[q], w, p[j]);
            }
        }
#pragma unroll
        for (int j = 0; j < 8; j++) acc[j] += (double)p[j];
    }
    double m = (double)mn[o], rs = 1.0 / sqrt((double)vr[o] + 1e-5);
    double s_ = (double)sc[o], b_ = (double)bi[o];
    double* xop = xo + ((size_t)bb * T_ + t0 + th * 8) * 128 + o;
#pragma unroll
    for (int j = 0; j < 8; j++) xop[(size_t)j * 128] = (acc[j] - m) * rs * s_ + b_;
}

// ---------------------------------------------------------------------------
// Kernel 6: ALIF scan per (b,c), C=128.
// ---------------------------------------------------------------------------
__global__ void alif(const double* __restrict__ xin, float* __restrict__ spk)
{
    int idx = blockIdx.x * blockDim.x + threadIdx.x;
    int b = idx >> 7, c = idx & 127;
    const double* xp = xin + (size_t)b * T_ * 128 + c;
    float* sp = spk + (size_t)b * T_ * 128 + c;
    double v = 0.0, th = 0.0, ps = 0.0;
    const double dd = 0.9, adp = 0.9, beta = 1.8;
    for (int t = 0; t < T_; t += 8) {
        double xv[8];
#pragma unroll
        for (int u = 0; u < 8; u++) xv[u] = xp[(size_t)(t + u) * 128];
#pragma unroll
        for (int u = 0; u < 8; u++) {
            th = th * adp + ps * beta;
            v = v * dd + xv[u];
            double vth = 0.5 + th;
            double s = (v - vth > 0.0) ? 1.0 : 0.0;
            v -= s * vth;
            ps = s;
            sp[(size_t)(t + u) * 128] = (float)s;
        }
    }
}

// ---------------------------------------------------------------------------
// Kernel 7: readout — dense + LI scan + dp + attention + logits. 1 block per b.
// ---------------------------------------------------------------------------
__global__ __launch_bounds__(256)
void readout(const float* __restrict__ spk3, const float* __restrict__ dw,
             const float* __restrict__ db, const float* __restrict__ a1w,
             const float* __restrict__ a1b, const float* __restrict__ a2w,
             const float* __restrict__ a2b, float* __restrict__ out)
{
    __shared__ double dl[480 * 4];
    __shared__ double dp[20 * 4];
    __shared__ double zl[20];
    __shared__ double red[1];
    int b = blockIdx.x, tid = threadIdx.x;
    const float* sp = spk3 + (size_t)b * T_ * 128;

    // dense: (480,128) @ (128,4) + bias
    for (int i = tid; i < 1920; i += 256) {
        int t = i >> 2, j = i & 3;
        const float* row = sp + (size_t)t * 128;
        double acc = 0.0;
        for (int c = 0; c < 128; c++)
            acc = fma((double)row[c], (double)dw[c * 4 + j], acc);
        dl[i] = acc + (double)db[j];
    }
    __syncthreads();
    // LI scan: v = v*0.9 + x*(1-0.9)
    if (tid < 4) {
        const double dec = 0.9, om = 1.0 - 0.9;
        double v = 0.0;
        for (int t = 0; t < T_; t++) {
            v = v * dec + dl[t * 4 + tid] * om;
            dl[t * 4 + tid] = v;
        }
    }
    __syncthreads();
    // dp = mean(last 12) - mean(first 12) per (g, j)
    if (tid < 80) {
        int g = tid >> 2, j = tid & 3;
        double s1 = 0.0, s2 = 0.0;
        for (int u = 0; u < 12; u++) {
            s1 += dl[(g * 24 + u) * 4 + j];
            s2 += dl[(g * 24 + 12 + u) * 4 + j];
        }
        dp[g * 4 + j] = s2 / 12.0 - s1 / 12.0;
    }
    __syncthreads();
    // z[g] = relu(dp@a1w + a1b) @ a2w + a2b
    if (tid < 20) {
        int g = tid;
        double z = (double)a2b[0];
        for (int i = 0; i < 8; i++) {
            double h = (double)a1b[i];
            for (int j = 0; j < 4; j++)
                h = fma(dp[g * 4 + j], (double)a1w[j * 8 + i], h);
            h = fmax(h, 0.0);
            z = fma(h, (double)a2w[i], z);
        }
        zl[g] = z;
    }
    __syncthreads();
    if (tid == 0) {
        double m = zl[0];
        for (int g = 1; g < 20; g++) m = fmax(m, zl[g]);
        double s = 0.0;
        for (int g = 0; g < 20; g++) { zl[g] = exp(zl[g] - m); s += zl[g]; }
        red[0] = s;
    }
    __syncthreads();
    if (tid < 4) {
        double s = red[0];
        double acc = 0.0;
        for (int g = 0; g < 20; g++) acc += dp[g * 4 + tid] * (zl[g] / s);
        out[b * 4 + tid] = (float)acc;
    }
}

// ---------------------------------------------------------------------------
extern "C" void kernel_launch(void* const* d_in, const int* in_sizes, int n_in,
                              void* d_out, int out_size, void* d_ws, size_t ws_size,
                              hipStream_t stream)
{
    const float* x     = (const float*)d_in[0];
    const float* w1    = (const float*)d_in[1];
    const float* bn1s  = (const float*)d_in[2];
    const float* bn1b  = (const float*)d_in[3];
    const float* bn1m  = (const float*)d_in[4];
    const float* bn1v  = (const float*)d_in[5];
    const float* vth1  = (const float*)d_in[6];
    const float* dec1  = (const float*)d_in[7];
    const float* w2    = (const float*)d_in[8];
    const float* bn2s  = (const float*)d_in[9];
    const float* bn2b  = (const float*)d_in[10];
    const float* bn2m  = (const float*)d_in[11];
    const float* bn2v  = (const float*)d_in[12];
    const float* vth2  = (const float*)d_in[13];
    const float* dec2  = (const float*)d_in[14];
    const float* w3    = (const float*)d_in[15];
    const float* bn3s  = (const float*)d_in[16];
    const float* bn3b  = (const float*)d_in[17];
    const float* bn3m  = (const float*)d_in[18];
    const float* bn3v  = (const float*)d_in[19];
    const float* dw    = (const float*)d_in[20];
    const float* db    = (const float*)d_in[21];
    const float* a1w   = (const float*)d_in[22];
    const float* a1b   = (const float*)d_in[23];
    const float* a2w   = (const float*)d_in[24];
    const float* a2b   = (const float*)d_in[25];

    float* out = (float*)d_out;
    double* xbuf = (double*)d_ws;                         // 61440*128 doubles = 62.9 MB
    float* zrow = (float*)(xbuf + (size_t)BT_ * 128);     // 128 zero floats for conv3 OOB

    // Stage 1
    conv1_bn<<<BT_ / 4, 256, 0, stream>>>(x, w1, bn1s, bn1b, bn1m, bn1v, xbuf, zrow);
    hlif<<<(B_ * 64) / 256, 256, 0, stream>>>(xbuf, out + OUT_SPK1, vth1, dec1, 64);
    // Stage 2
    conv2_bn<<<B_ * 30, 256, 0, stream>>>(out + OUT_SPK1, w2, bn2s, bn2b, bn2m, bn2v, xbuf);
    hlif<<<(B_ * 128) / 256, 256, 0, stream>>>(xbuf, out + OUT_SPK2, vth2, dec2, 128);
    // Stage 3
    conv3_bn<<<B_ * 30, 256, 0, stream>>>(out + OUT_SPK2, w3, bn3s, bn3b, bn3m, bn3v, zrow, xbuf);
    alif<<<(B_ * 128) / 256, 256, 0, stream>>>(xbuf, out + OUT_SPK3);
    // Readout
    readout<<<B_, 256, 0, stream>>>(out + OUT_SPK3, dw, db, a1w, a1b, a2w, a2b, out);
}

// Round 7
// 2196.086 us; speedup vs baseline: 6.4269x; 2.0958x over previous
//
#include <hip/hip_runtime.h>
#include <cmath>

#define B_ 128
#define T_ 480
#define BT_ 61440

// output layout (fp32 elements)
#define OUT_SPK1 512
#define OUT_SPK2 3932672
#define OUT_SPK3 11796992

__device__ __forceinline__ double softplus_d(double x) {
    return (x > 0.0) ? (x + log1p(exp(-x))) : log1p(exp(x));
}
__device__ __forceinline__ double sigmoid_d(double x) {
    return 1.0 / (1.0 + exp(-x));
}

// ---------------------------------------------------------------------------
// Kernel 1: conv1 (61440x64 @ 64x64) + bn1 -> xbuf (f64).
// ---------------------------------------------------------------------------
__global__ __launch_bounds__(256)
void conv1_bn(const float* __restrict__ x, const float* __restrict__ w1,
              const float* __restrict__ sc, const float* __restrict__ bi,
              const float* __restrict__ mn, const float* __restrict__ vr,
              double* __restrict__ xo)
{
    __shared__ float wl[64 * 64];
    __shared__ float xl[4 * 64];
    int tid = threadIdx.x;
#pragma unroll
    for (int i = 0; i < 16; i++) wl[tid + 256 * i] = w1[tid + 256 * i];
    int row0 = blockIdx.x * 4;
    xl[tid] = x[(size_t)row0 * 64 + tid];
    __syncthreads();
    int o = tid & 63, r = tid >> 6;
    double acc = 0.0;
#pragma unroll
    for (int w = 0; w < 64; w++)
        acc = fma((double)xl[r * 64 + w], (double)wl[w * 64 + o], acc);
    double y = (acc - (double)mn[o]) * (1.0 / sqrt((double)vr[o] + 1e-5)) * (double)sc[o]
             + (double)bi[o];
    xo[(size_t)(row0 + r) * 64 + o] = y;
}

// ---------------------------------------------------------------------------
// Kernel 2/4: HLIF scan over T per (b,c).
// ---------------------------------------------------------------------------
__global__ void hlif(const double* __restrict__ xin, float* __restrict__ spk,
                     const float* __restrict__ vth_raw, const float* __restrict__ dec_raw,
                     int C)
{
    int idx = blockIdx.x * blockDim.x + threadIdx.x;
    int b = idx / C, c = idx - b * C;
    double vth = softplus_d((double)vth_raw[c]) + 0.5;
    double dec = sigmoid_d((double)dec_raw[c] + 2.0);
    dec = fmin(fmax(dec, 0.0), 0.99);
    const double* xp = xin + (size_t)b * T_ * C + c;
    float* sp = spk + (size_t)b * T_ * C + c;
    double v = 0.0;
    for (int t = 0; t < T_; t += 8) {
        double xv[8];
#pragma unroll
        for (int u = 0; u < 8; u++) xv[u] = xp[(size_t)(t + u) * C];
#pragma unroll
        for (int u = 0; u < 8; u++) {
            v = v * dec + xv[u];
            double s = (v - vth > 0.0) ? 1.0 : 0.0;
            v -= s * vth;
            sp[(size_t)(t + u) * C] = (float)s;
        }
    }
}

// ---------------------------------------------------------------------------
// XCD-locality block swizzle for conv2's 128b x 30tt grid (3840 blocks).
// ---------------------------------------------------------------------------
__device__ __forceinline__ void swz_b_tt(int j, int& bb, int& tt) {
    int xcd = j & 7, slot = j >> 3;       // slot in [0,480)
    bb = xcd + 8 * (slot / 30);           // 16 b's per XCD
    tt = slot % 30;
}

// ---------------------------------------------------------------------------
// Kernel 3: conv2 (K=32, dil=4, pad 62, Cin=64, Cout=128) + bn2 -> xbuf (f64)
// Hybrid precision: per-k 64-term partial in f32 (fmac, no cvt), k-sum in f64.
// ---------------------------------------------------------------------------
__global__ __launch_bounds__(256)
void conv2_bn(const float* __restrict__ spk1, const float* __restrict__ w2,
              const float* __restrict__ sc, const float* __restrict__ bi,
              const float* __restrict__ mn, const float* __restrict__ vr,
              double* __restrict__ xo)
{
    __shared__ float S[140 * 64];   // rows t0-62 .. t0+15+62
    int tid = threadIdx.x;
    int bb, tt;
    swz_b_tt(blockIdx.x, bb, tt);
    int t0 = tt * 16;
    const float* sb = spk1 + (size_t)bb * T_ * 64;
    for (int i = tid; i < 140 * 64; i += 256) {
        int rr = i >> 6, cc = i & 63;
        int t = t0 - 62 + rr;
        S[i] = (t >= 0 && t < T_) ? sb[(size_t)t * 64 + cc] : 0.0f;
    }
    __syncthreads();
    int o = tid & 127, th = tid >> 7;
    double acc[8];
#pragma unroll
    for (int j = 0; j < 8; j++) acc[j] = 0.0;

    for (int k = 0; k < 32; k++) {
        int rbase = th * 8 + 4 * k;   // row for (j) = rbase + j
        const float* wp = w2 + (size_t)k * 64 * 128 + o;
        float p[8];
#pragma unroll
        for (int j = 0; j < 8; j++) p[j] = 0.0f;
        for (int cc = 0; cc < 64; cc += 4) {
            float4 sv[8];
#pragma unroll
            for (int j = 0; j < 8; j++)
                sv[j] = *(const float4*)&S[(rbase + j) * 64 + cc];
#pragma unroll
            for (int q = 0; q < 4; q++) {
                float w = wp[(size_t)(cc + q) * 128];
#pragma unroll
                for (int j = 0; j < 8; j++)
                    p[j] = fmaf(((const float*)&sv[j])[q], w, p[j]);
            }
        }
#pragma unroll
        for (int j = 0; j < 8; j++) acc[j] += (double)p[j];
    }
    double m = (double)mn[o], rs = 1.0 / sqrt((double)vr[o] + 1e-5);
    double s_ = (double)sc[o], b_ = (double)bi[o];
    double* xop = xo + ((size_t)bb * T_ + t0 + th * 8) * 128 + o;
#pragma unroll
    for (int j = 0; j < 8; j++) xop[(size_t)j * 128] = (acc[j] - m) * rs * s_ + b_;
}

// ---------------------------------------------------------------------------
// Kernel 5: conv3 (K=32, dil=12, pad 186, Cin=128, Cout=128) + bn3 -> xbuf
// Residue-class decomposition: t mod 12 classes decouple -> per (b, rho) this
// is a dilation-1 K=32 conv over 40 rows. Stage the zero-padded 72-row window
// in LDS (36 KB), inner loop = conv2's proven LDS-broadcast structure.
// Per-accumulator FMA order (k asc, cc asc, q asc; zero taps exact) is
// bitwise identical to the previous kernel.
// Block: 256 thr = 64 o-lanes x 4 th; each thread: 10 rows x 2 o-cols.
// ---------------------------------------------------------------------------
__global__ __launch_bounds__(256)
void conv3_bn(const float* __restrict__ spk2, const float* __restrict__ w3,
              const float* __restrict__ sc, const float* __restrict__ bi,
              const float* __restrict__ mn, const float* __restrict__ vr,
              double* __restrict__ xo)
{
    __shared__ float S[72 * 128];   // padded class window, 36 KB
    int tid = threadIdx.x;
    // XCD swizzle: grid 1536 = 8 xcd * (16 b * 12 rho)
    int jj = blockIdx.x;
    int xcd = jj & 7, slot = jj >> 3;         // slot in [0,192)
    int bb = xcd + 8 * (slot / 12);
    int rho = slot % 12;
    int rhop = (rho < 6) ? rho + 6 : rho - 6; // source class
    int koff = (rho < 6) ? 0 : 1;             // idx = r + k + koff
    const float* sb = spk2 + (size_t)bb * T_ * 128;

    // stage: S[idx][cc] = class row m = idx-16 (zero outside [0,40))
    for (int i = tid; i < 72 * 128; i += 256) {
        int idx = i >> 7, cc = i & 127;
        int m = idx - 16;
        S[i] = (m >= 0 && m < 40) ? sb[(size_t)(12 * m + rhop) * 128 + cc] : 0.0f;
    }
    __syncthreads();

    int o = tid & 63, th = tid >> 6;          // wave-uniform th
    double acc[10][2];
#pragma unroll
    for (int r = 0; r < 10; r++) { acc[r][0] = 0.0; acc[r][1] = 0.0; }

    for (int k = 0; k < 32; k++) {
        const float* wp = w3 + (size_t)k * 128 * 128;
        int base = th * 10 + k + koff;        // LDS row for r=0
        float p[10][2];
#pragma unroll
        for (int r = 0; r < 10; r++) { p[r][0] = 0.0f; p[r][1] = 0.0f; }
        for (int cc = 0; cc < 128; cc += 4) {
            float w00 = wp[(size_t)(cc + 0) * 128 + o];
            float w01 = wp[(size_t)(cc + 0) * 128 + o + 64];
            float w10 = wp[(size_t)(cc + 1) * 128 + o];
            float w11 = wp[(size_t)(cc + 1) * 128 + o + 64];
            float w20 = wp[(size_t)(cc + 2) * 128 + o];
            float w21 = wp[(size_t)(cc + 2) * 128 + o + 64];
            float w30 = wp[(size_t)(cc + 3) * 128 + o];
            float w31 = wp[(size_t)(cc + 3) * 128 + o + 64];
#pragma unroll
            for (int r = 0; r < 10; r++) {
                float4 sv = *(const float4*)&S[(base + r) * 128 + cc];
                p[r][0] = fmaf(sv.x, w00, p[r][0]);
                p[r][1] = fmaf(sv.x, w01, p[r][1]);
                p[r][0] = fmaf(sv.y, w10, p[r][0]);
                p[r][1] = fmaf(sv.y, w11, p[r][1]);
                p[r][0] = fmaf(sv.z, w20, p[r][0]);
                p[r][1] = fmaf(sv.z, w21, p[r][1]);
                p[r][0] = fmaf(sv.w, w30, p[r][0]);
                p[r][1] = fmaf(sv.w, w31, p[r][1]);
            }
        }
#pragma unroll
        for (int r = 0; r < 10; r++) {
            acc[r][0] += (double)p[r][0];
            acc[r][1] += (double)p[r][1];
        }
    }

    double m0 = (double)mn[o],      rs0 = 1.0 / sqrt((double)vr[o] + 1e-5);
    double s0 = (double)sc[o],      b0  = (double)bi[o];
    double m1 = (double)mn[o + 64], rs1 = 1.0 / sqrt((double)vr[o + 64] + 1e-5);
    double s1 = (double)sc[o + 64], b1  = (double)bi[o + 64];
#pragma unroll
    for (int r = 0; r < 10; r++) {
        int t_out = 12 * (th * 10 + r) + rho;
        double* xop = xo + ((size_t)bb * T_ + t_out) * 128;
        xop[o]      = (acc[r][0] - m0) * rs0 * s0 + b0;
        xop[o + 64] = (acc[r][1] - m1) * rs1 * s1 + b1;
    }
}

// ---------------------------------------------------------------------------
// Kernel 6: ALIF scan per (b,c), C=128.
// ---------------------------------------------------------------------------
__global__ void alif(const double* __restrict__ xin, float* __restrict__ spk)
{
    int idx = blockIdx.x * blockDim.x + threadIdx.x;
    int b = idx >> 7, c = idx & 127;
    const double* xp = xin + (size_t)b * T_ * 128 + c;
    float* sp = spk + (size_t)b * T_ * 128 + c;
    double v = 0.0, th = 0.0, ps = 0.0;
    const double dd = 0.9, adp = 0.9, beta = 1.8;
    for (int t = 0; t < T_; t += 8) {
        double xv[8];
#pragma unroll
        for (int u = 0; u < 8; u++) xv[u] = xp[(size_t)(t + u) * 128];
#pragma unroll
        for (int u = 0; u < 8; u++) {
            th = th * adp + ps * beta;
            v = v * dd + xv[u];
            double vth = 0.5 + th;
            double s = (v - vth > 0.0) ? 1.0 : 0.0;
            v -= s * vth;
            ps = s;
            sp[(size_t)(t + u) * 128] = (float)s;
        }
    }
}

// ---------------------------------------------------------------------------
// Kernel 7: readout — dense + LI scan + dp + attention + logits. 1 block per b.
// ---------------------------------------------------------------------------
__global__ __launch_bounds__(256)
void readout(const float* __restrict__ spk3, const float* __restrict__ dw,
             const float* __restrict__ db, const float* __restrict__ a1w,
             const float* __restrict__ a1b, const float* __restrict__ a2w,
             const float* __restrict__ a2b, float* __restrict__ out)
{
    __shared__ double dl[480 * 4];
    __shared__ double dp[20 * 4];
    __shared__ double zl[20];
    __shared__ double red[1];
    int b = blockIdx.x, tid = threadIdx.x;
    const float* sp = spk3 + (size_t)b * T_ * 128;

    // dense: (480,128) @ (128,4) + bias
    for (int i = tid; i < 1920; i += 256) {
        int t = i >> 2, j = i & 3;
        const float* row = sp + (size_t)t * 128;
        double acc = 0.0;
        for (int c = 0; c < 128; c++)
            acc = fma((double)row[c], (double)dw[c * 4 + j], acc);
        dl[i] = acc + (double)db[j];
    }
    __syncthreads();
    // LI scan: v = v*0.9 + x*(1-0.9)
    if (tid < 4) {
        const double dec = 0.9, om = 1.0 - 0.9;
        double v = 0.0;
        for (int t = 0; t < T_; t++) {
            v = v * dec + dl[t * 4 + tid] * om;
            dl[t * 4 + tid] = v;
        }
    }
    __syncthreads();
    // dp = mean(last 12) - mean(first 12) per (g, j)
    if (tid < 80) {
        int g = tid >> 2, j = tid & 3;
        double s1 = 0.0, s2 = 0.0;
        for (int u = 0; u < 12; u++) {
            s1 += dl[(g * 24 + u) * 4 + j];
            s2 += dl[(g * 24 + 12 + u) * 4 + j];
        }
        dp[g * 4 + j] = s2 / 12.0 - s1 / 12.0;
    }
    __syncthreads();
    // z[g] = relu(dp@a1w + a1b) @ a2w + a2b
    if (tid < 20) {
        int g = tid;
        double z = (double)a2b[0];
        for (int i = 0; i < 8; i++) {
            double h = (double)a1b[i];
            for (int j = 0; j < 4; j++)
                h = fma(dp[g * 4 + j], (double)a1w[j * 8 + i], h);
            h = fmax(h, 0.0);
            z = fma(h, (double)a2w[i], z);
        }
        zl[g] = z;
    }
    __syncthreads();
    if (tid == 0) {
        double m = zl[0];
        for (int g = 1; g < 20; g++) m = fmax(m, zl[g]);
        double s = 0.0;
        for (int g = 0; g < 20; g++) { zl[g] = exp(zl[g] - m); s += zl[g]; }
        red[0] = s;
    }
    __syncthreads();
    if (tid < 4) {
        double s = red[0];
        double acc = 0.0;
        for (int g = 0; g < 20; g++) acc += dp[g * 4 + tid] * (zl[g] / s);
        out[b * 4 + tid] = (float)acc;
    }
}

// ---------------------------------------------------------------------------
extern "C" void kernel_launch(void* const* d_in, const int* in_sizes, int n_in,
                              void* d_out, int out_size, void* d_ws, size_t ws_size,
                              hipStream_t stream)
{
    const float* x     = (const float*)d_in[0];
    const float* w1    = (const float*)d_in[1];
    const float* bn1s  = (const float*)d_in[2];
    const float* bn1b  = (const float*)d_in[3];
    const float* bn1m  = (const float*)d_in[4];
    const float* bn1v  = (const float*)d_in[5];
    const float* vth1  = (const float*)d_in[6];
    const float* dec1  = (const float*)d_in[7];
    const float* w2    = (const float*)d_in[8];
    const float* bn2s  = (const float*)d_in[9];
    const float* bn2b  = (const float*)d_in[10];
    const float* bn2m  = (const float*)d_in[11];
    const float* bn2v  = (const float*)d_in[12];
    const float* vth2  = (const float*)d_in[13];
    const float* dec2  = (const float*)d_in[14];
    const float* w3    = (const float*)d_in[15];
    const float* bn3s  = (const float*)d_in[16];
    const float* bn3b  = (const float*)d_in[17];
    const float* bn3m  = (const float*)d_in[18];
    const float* bn3v  = (const float*)d_in[19];
    const float* dw    = (const float*)d_in[20];
    const float* db    = (const float*)d_in[21];
    const float* a1w   = (const float*)d_in[22];
    const float* a1b   = (const float*)d_in[23];
    const float* a2w   = (const float*)d_in[24];
    const float* a2b   = (const float*)d_in[25];

    float* out = (float*)d_out;
    double* xbuf = (double*)d_ws;                         // 61440*128 doubles = 62.9 MB

    // Stage 1
    conv1_bn<<<BT_ / 4, 256, 0, stream>>>(x, w1, bn1s, bn1b, bn1m, bn1v, xbuf);
    hlif<<<(B_ * 64) / 256, 256, 0, stream>>>(xbuf, out + OUT_SPK1, vth1, dec1, 64);
    // Stage 2
    conv2_bn<<<B_ * 30, 256, 0, stream>>>(out + OUT_SPK1, w2, bn2s, bn2b, bn2m, bn2v, xbuf);
    hlif<<<(B_ * 128) / 256, 256, 0, stream>>>(xbuf, out + OUT_SPK2, vth2, dec2, 128);
    // Stage 3
    conv3_bn<<<B_ * 12, 256, 0, stream>>>(out + OUT_SPK2, w3, bn3s, bn3b, bn3m, bn3v, xbuf);
    alif<<<(B_ * 128) / 256, 256, 0, stream>>>(xbuf, out + OUT_SPK3);
    // Readout
    readout<<<B_, 256, 0, stream>>>(out + OUT_SPK3, dw, db, a1w, a1b, a2w, a2b, out);
}

// Round 8
// 1809.852 us; speedup vs baseline: 7.7984x; 1.2134x over previous
//
#include <hip/hip_runtime.h>
#include <cmath>

#define B_ 128
#define T_ 480
#define BT_ 61440

// output layout (fp32 elements)
#define OUT_SPK1 512
#define OUT_SPK2 3932672
#define OUT_SPK3 11796992

__device__ __forceinline__ double softplus_d(double x) {
    return (x > 0.0) ? (x + log1p(exp(-x))) : log1p(exp(x));
}
__device__ __forceinline__ double sigmoid_d(double x) {
    return 1.0 / (1.0 + exp(-x));
}

// ---------------------------------------------------------------------------
// Kernel 1: conv1 (61440x64 @ 64x64) + bn1 -> xbuf (f64).
// ---------------------------------------------------------------------------
__global__ __launch_bounds__(256)
void conv1_bn(const float* __restrict__ x, const float* __restrict__ w1,
              const float* __restrict__ sc, const float* __restrict__ bi,
              const float* __restrict__ mn, const float* __restrict__ vr,
              double* __restrict__ xo)
{
    __shared__ float wl[64 * 64];
    __shared__ float xl[4 * 64];
    int tid = threadIdx.x;
#pragma unroll
    for (int i = 0; i < 16; i++) wl[tid + 256 * i] = w1[tid + 256 * i];
    int row0 = blockIdx.x * 4;
    xl[tid] = x[(size_t)row0 * 64 + tid];
    __syncthreads();
    int o = tid & 63, r = tid >> 6;
    double acc = 0.0;
#pragma unroll
    for (int w = 0; w < 64; w++)
        acc = fma((double)xl[r * 64 + w], (double)wl[w * 64 + o], acc);
    double y = (acc - (double)mn[o]) * (1.0 / sqrt((double)vr[o] + 1e-5)) * (double)sc[o]
             + (double)bi[o];
    xo[(size_t)(row0 + r) * 64 + o] = y;
}

// ---------------------------------------------------------------------------
// Kernel 2/4: HLIF scan over T per (b,c).
// ---------------------------------------------------------------------------
__global__ void hlif(const double* __restrict__ xin, float* __restrict__ spk,
                     const float* __restrict__ vth_raw, const float* __restrict__ dec_raw,
                     int C)
{
    int idx = blockIdx.x * blockDim.x + threadIdx.x;
    int b = idx / C, c = idx - b * C;
    double vth = softplus_d((double)vth_raw[c]) + 0.5;
    double dec = sigmoid_d((double)dec_raw[c] + 2.0);
    dec = fmin(fmax(dec, 0.0), 0.99);
    const double* xp = xin + (size_t)b * T_ * C + c;
    float* sp = spk + (size_t)b * T_ * C + c;
    double v = 0.0;
    for (int t = 0; t < T_; t += 8) {
        double xv[8];
#pragma unroll
        for (int u = 0; u < 8; u++) xv[u] = xp[(size_t)(t + u) * C];
#pragma unroll
        for (int u = 0; u < 8; u++) {
            v = v * dec + xv[u];
            double s = (v - vth > 0.0) ? 1.0 : 0.0;
            v -= s * vth;
            sp[(size_t)(t + u) * C] = (float)s;
        }
    }
}

// ---------------------------------------------------------------------------
// XCD-locality block swizzle for conv2's 128b x 30tt grid (3840 blocks).
// ---------------------------------------------------------------------------
__device__ __forceinline__ void swz_b_tt(int j, int& bb, int& tt) {
    int xcd = j & 7, slot = j >> 3;       // slot in [0,480)
    bb = xcd + 8 * (slot / 30);           // 16 b's per XCD
    tt = slot % 30;
}

// ---------------------------------------------------------------------------
// Kernel 3: conv2 (K=32, dil=4, pad 62, Cin=64, Cout=128) + bn2 -> xbuf (f64)
// Hybrid precision: per-k 64-term partial in f32 (fmac, no cvt), k-sum in f64.
// ---------------------------------------------------------------------------
__global__ __launch_bounds__(256)
void conv2_bn(const float* __restrict__ spk1, const float* __restrict__ w2,
              const float* __restrict__ sc, const float* __restrict__ bi,
              const float* __restrict__ mn, const float* __restrict__ vr,
              double* __restrict__ xo)
{
    __shared__ float S[140 * 64];   // rows t0-62 .. t0+15+62
    int tid = threadIdx.x;
    int bb, tt;
    swz_b_tt(blockIdx.x, bb, tt);
    int t0 = tt * 16;
    const float* sb = spk1 + (size_t)bb * T_ * 64;
    for (int i = tid; i < 140 * 64; i += 256) {
        int rr = i >> 6, cc = i & 63;
        int t = t0 - 62 + rr;
        S[i] = (t >= 0 && t < T_) ? sb[(size_t)t * 64 + cc] : 0.0f;
    }
    __syncthreads();
    int o = tid & 127, th = tid >> 7;
    double acc[8];
#pragma unroll
    for (int j = 0; j < 8; j++) acc[j] = 0.0;

    for (int k = 0; k < 32; k++) {
        int rbase = th * 8 + 4 * k;   // row for (j) = rbase + j
        const float* wp = w2 + (size_t)k * 64 * 128 + o;
        float p[8];
#pragma unroll
        for (int j = 0; j < 8; j++) p[j] = 0.0f;
        for (int cc = 0; cc < 64; cc += 4) {
            float4 sv[8];
#pragma unroll
            for (int j = 0; j < 8; j++)
                sv[j] = *(const float4*)&S[(rbase + j) * 64 + cc];
#pragma unroll
            for (int q = 0; q < 4; q++) {
                float w = wp[(size_t)(cc + q) * 128];
#pragma unroll
                for (int j = 0; j < 8; j++)
                    p[j] = fmaf(((const float*)&sv[j])[q], w, p[j]);
            }
        }
#pragma unroll
        for (int j = 0; j < 8; j++) acc[j] += (double)p[j];
    }
    double m = (double)mn[o], rs = 1.0 / sqrt((double)vr[o] + 1e-5);
    double s_ = (double)sc[o], b_ = (double)bi[o];
    double* xop = xo + ((size_t)bb * T_ + t0 + th * 8) * 128 + o;
#pragma unroll
    for (int j = 0; j < 8; j++) xop[(size_t)j * 128] = (acc[j] - m) * rs * s_ + b_;
}

// ---------------------------------------------------------------------------
// Kernel 5: conv3 (K=32, dil=12, pad 186, Cin=128, Cout=128) + bn3 -> xbuf
// Residue-class decomposition (t mod 12) + cc-chunk-outer loop with a
// 10-slot rolling register window over LDS rows: 41 ds_read_b128 per chunk
// instead of 320 (k-adjacent row reuse). LDS = 40 real rows + 1 zero row
// (20.5 KB), branchless wave-uniform row clamp. Fully unrolled k-loop gives
// static (k+r)%10 slot indices (no scratch).
// Per-accumulator FMA order: chunk asc, k asc, q asc (f32 partial per chunk,
// f64 chunk-sum) — same exact products, reordered partials.
// ---------------------------------------------------------------------------
__global__ __launch_bounds__(256)
void conv3_bn(const float* __restrict__ spk2, const float* __restrict__ w3,
              const float* __restrict__ sc, const float* __restrict__ bi,
              const float* __restrict__ mn, const float* __restrict__ vr,
              double* __restrict__ xo)
{
    __shared__ float S[41 * 128];   // 40 class rows + 1 zero row (20.5 KB)
    int tid = threadIdx.x;
    // XCD swizzle: grid 1536 = 8 xcd * (16 b * 12 rho)
    int jj = blockIdx.x;
    int xcd = jj & 7, slot = jj >> 3;         // slot in [0,192)
    int bb = xcd + 8 * (slot / 12);
    int rho = slot % 12;
    int rhop = (rho < 6) ? rho + 6 : rho - 6; // source class
    int koff = (rho < 6) ? 0 : 1;
    const float* sb = spk2 + (size_t)bb * T_ * 128;

    for (int i = tid; i < 41 * 128; i += 256) {
        int idx = i >> 7, cc = i & 127;
        S[i] = (idx < 40) ? sb[(size_t)(12 * idx + rhop) * 128 + cc] : 0.0f;
    }
    __syncthreads();

    int o = tid & 63, th = tid >> 6;          // wave-uniform th
    int base_r = th * 10 + koff - 16;         // class row for (k=0, r=0)
    const float4* S4 = (const float4*)S;

    double acc[10][2];
#pragma unroll
    for (int r = 0; r < 10; r++) { acc[r][0] = 0.0; acc[r][1] = 0.0; }

    for (int ch = 0; ch < 32; ch++) {
        float4 w[10];
#pragma unroll
        for (int s = 0; s < 10; s++) {
            int m = base_r + s;
            int row = ((unsigned)m < 40u) ? m : 40;   // zero row
            w[s] = S4[row * 32 + ch];
        }
        float p[10][2];
#pragma unroll
        for (int r = 0; r < 10; r++) { p[r][0] = 0.0f; p[r][1] = 0.0f; }

        const float* wpc = w3 + (size_t)ch * 512 + o;
#pragma unroll
        for (int k = 0; k < 32; k++) {
            const float* wp = wpc + (size_t)k * 16384;
            float w00 = wp[0],   w01 = wp[64];
            float w10 = wp[128], w11 = wp[192];
            float w20 = wp[256], w21 = wp[320];
            float w30 = wp[384], w31 = wp[448];
#pragma unroll
            for (int r = 0; r < 10; r++) {
                float4 sv = w[(k + r) % 10];
                p[r][0] = fmaf(sv.x, w00, p[r][0]);
                p[r][1] = fmaf(sv.x, w01, p[r][1]);
                p[r][0] = fmaf(sv.y, w10, p[r][0]);
                p[r][1] = fmaf(sv.y, w11, p[r][1]);
                p[r][0] = fmaf(sv.z, w20, p[r][0]);
                p[r][1] = fmaf(sv.z, w21, p[r][1]);
                p[r][0] = fmaf(sv.w, w30, p[r][0]);
                p[r][1] = fmaf(sv.w, w31, p[r][1]);
            }
            if (k < 31) {
                int m = base_r + k + 10;
                int row = ((unsigned)m < 40u) ? m : 40;
                w[k % 10] = S4[row * 32 + ch];
            }
        }
#pragma unroll
        for (int r = 0; r < 10; r++) {
            acc[r][0] += (double)p[r][0];
            acc[r][1] += (double)p[r][1];
        }
    }

    double m0 = (double)mn[o],      rs0 = 1.0 / sqrt((double)vr[o] + 1e-5);
    double s0 = (double)sc[o],      b0  = (double)bi[o];
    double m1 = (double)mn[o + 64], rs1 = 1.0 / sqrt((double)vr[o + 64] + 1e-5);
    double s1 = (double)sc[o + 64], b1  = (double)bi[o + 64];
#pragma unroll
    for (int r = 0; r < 10; r++) {
        int t_out = 12 * (th * 10 + r) + rho;
        double* xop = xo + ((size_t)bb * T_ + t_out) * 128;
        xop[o]      = (acc[r][0] - m0) * rs0 * s0 + b0;
        xop[o + 64] = (acc[r][1] - m1) * rs1 * s1 + b1;
    }
}

// ---------------------------------------------------------------------------
// Kernel 6: ALIF scan per (b,c), C=128.
// ---------------------------------------------------------------------------
__global__ void alif(const double* __restrict__ xin, float* __restrict__ spk)
{
    int idx = blockIdx.x * blockDim.x + threadIdx.x;
    int b = idx >> 7, c = idx & 127;
    const double* xp = xin + (size_t)b * T_ * 128 + c;
    float* sp = spk + (size_t)b * T_ * 128 + c;
    double v = 0.0, th = 0.0, ps = 0.0;
    const double dd = 0.9, adp = 0.9, beta = 1.8;
    for (int t = 0; t < T_; t += 8) {
        double xv[8];
#pragma unroll
        for (int u = 0; u < 8; u++) xv[u] = xp[(size_t)(t + u) * 128];
#pragma unroll
        for (int u = 0; u < 8; u++) {
            th = th * adp + ps * beta;
            v = v * dd + xv[u];
            double vth = 0.5 + th;
            double s = (v - vth > 0.0) ? 1.0 : 0.0;
            v -= s * vth;
            ps = s;
            sp[(size_t)(t + u) * 128] = (float)s;
        }
    }
}

// ---------------------------------------------------------------------------
// Kernel 7: readout — dense + LI scan + dp + attention + logits. 1 block per b.
// ---------------------------------------------------------------------------
__global__ __launch_bounds__(256)
void readout(const float* __restrict__ spk3, const float* __restrict__ dw,
             const float* __restrict__ db, const float* __restrict__ a1w,
             const float* __restrict__ a1b, const float* __restrict__ a2w,
             const float* __restrict__ a2b, float* __restrict__ out)
{
    __shared__ double dl[480 * 4];
    __shared__ double dp[20 * 4];
    __shared__ double zl[20];
    __shared__ double red[1];
    int b = blockIdx.x, tid = threadIdx.x;
    const float* sp = spk3 + (size_t)b * T_ * 128;

    // dense: (480,128) @ (128,4) + bias
    for (int i = tid; i < 1920; i += 256) {
        int t = i >> 2, j = i & 3;
        const float* row = sp + (size_t)t * 128;
        double acc = 0.0;
        for (int c = 0; c < 128; c++)
            acc = fma((double)row[c], (double)dw[c * 4 + j], acc);
        dl[i] = acc + (double)db[j];
    }
    __syncthreads();
    // LI scan: v = v*0.9 + x*(1-0.9)
    if (tid < 4) {
        const double dec = 0.9, om = 1.0 - 0.9;
        double v = 0.0;
        for (int t = 0; t < T_; t++) {
            v = v * dec + dl[t * 4 + tid] * om;
            dl[t * 4 + tid] = v;
        }
    }
    __syncthreads();
    // dp = mean(last 12) - mean(first 12) per (g, j)
    if (tid < 80) {
        int g = tid >> 2, j = tid & 3;
        double s1 = 0.0, s2 = 0.0;
        for (int u = 0; u < 12; u++) {
            s1 += dl[(g * 24 + u) * 4 + j];
            s2 += dl[(g * 24 + 12 + u) * 4 + j];
        }
        dp[g * 4 + j] = s2 / 12.0 - s1 / 12.0;
    }
    __syncthreads();
    // z[g] = relu(dp@a1w + a1b) @ a2w + a2b
    if (tid < 20) {
        int g = tid;
        double z = (double)a2b[0];
        for (int i = 0; i < 8; i++) {
            double h = (double)a1b[i];
            for (int j = 0; j < 4; j++)
                h = fma(dp[g * 4 + j], (double)a1w[j * 8 + i], h);
            h = fmax(h, 0.0);
            z = fma(h, (double)a2w[i], z);
        }
        zl[g] = z;
    }
    __syncthreads();
    if (tid == 0) {
        double m = zl[0];
        for (int g = 1; g < 20; g++) m = fmax(m, zl[g]);
        double s = 0.0;
        for (int g = 0; g < 20; g++) { zl[g] = exp(zl[g] - m); s += zl[g]; }
        red[0] = s;
    }
    __syncthreads();
    if (tid < 4) {
        double s = red[0];
        double acc = 0.0;
        for (int g = 0; g < 20; g++) acc += dp[g * 4 + tid] * (zl[g] / s);
        out[b * 4 + tid] = (float)acc;
    }
}

// ---------------------------------------------------------------------------
extern "C" void kernel_launch(void* const* d_in, const int* in_sizes, int n_in,
                              void* d_out, int out_size, void* d_ws, size_t ws_size,
                              hipStream_t stream)
{
    const float* x     = (const float*)d_in[0];
    const float* w1    = (const float*)d_in[1];
    const float* bn1s  = (const float*)d_in[2];
    const float* bn1b  = (const float*)d_in[3];
    const float* bn1m  = (const float*)d_in[4];
    const float* bn1v  = (const float*)d_in[5];
    const float* vth1  = (const float*)d_in[6];
    const float* dec1  = (const float*)d_in[7];
    const float* w2    = (const float*)d_in[8];
    const float* bn2s  = (const float*)d_in[9];
    const float* bn2b  = (const float*)d_in[10];
    const float* bn2m  = (const float*)d_in[11];
    const float* bn2v  = (const float*)d_in[12];
    const float* vth2  = (const float*)d_in[13];
    const float* dec2  = (const float*)d_in[14];
    const float* w3    = (const float*)d_in[15];
    const float* bn3s  = (const float*)d_in[16];
    const float* bn3b  = (const float*)d_in[17];
    const float* bn3m  = (const float*)d_in[18];
    const float* bn3v  = (const float*)d_in[19];
    const float* dw    = (const float*)d_in[20];
    const float* db    = (const float*)d_in[21];
    const float* a1w   = (const float*)d_in[22];
    const float* a1b   = (const float*)d_in[23];
    const float* a2w   = (const float*)d_in[24];
    const float* a2b   = (const float*)d_in[25];

    float* out = (float*)d_out;
    double* xbuf = (double*)d_ws;                         // 61440*128 doubles = 62.9 MB

    // Stage 1
    conv1_bn<<<BT_ / 4, 256, 0, stream>>>(x, w1, bn1s, bn1b, bn1m, bn1v, xbuf);
    hlif<<<(B_ * 64) / 256, 256, 0, stream>>>(xbuf, out + OUT_SPK1, vth1, dec1, 64);
    // Stage 2
    conv2_bn<<<B_ * 30, 256, 0, stream>>>(out + OUT_SPK1, w2, bn2s, bn2b, bn2m, bn2v, xbuf);
    hlif<<<(B_ * 128) / 256, 256, 0, stream>>>(xbuf, out + OUT_SPK2, vth2, dec2, 128);
    // Stage 3
    conv3_bn<<<B_ * 12, 256, 0, stream>>>(out + OUT_SPK2, w3, bn3s, bn3b, bn3m, bn3v, xbuf);
    alif<<<(B_ * 128) / 256, 256, 0, stream>>>(xbuf, out + OUT_SPK3);
    // Readout
    readout<<<B_, 256, 0, stream>>>(out + OUT_SPK3, dw, db, a1w, a1b, a2w, a2b, out);
}

// Round 10
// 1142.326 us; speedup vs baseline: 12.3554x; 1.5844x over previous
//
#include <hip/hip_runtime.h>
#include <cmath>

#define B_ 128
#define T_ 480
#define BT_ 61440

// output layout (fp32 elements)
#define OUT_SPK1 512
#define OUT_SPK2 3932672
#define OUT_SPK3 11796992

typedef __attribute__((ext_vector_type(4))) int i32x4;

__device__ __forceinline__ double softplus_d(double x) {
    return (x > 0.0) ? (x + log1p(exp(-x))) : log1p(exp(x));
}
__device__ __forceinline__ double sigmoid_d(double x) {
    return 1.0 / (1.0 + exp(-x));
}

// ---------------------------------------------------------------------------
// Kernel 1: conv1 (61440x64 @ 64x64) + bn1 -> xbuf (f64).
// ---------------------------------------------------------------------------
__global__ __launch_bounds__(256)
void conv1_bn(const float* __restrict__ x, const float* __restrict__ w1,
              const float* __restrict__ sc, const float* __restrict__ bi,
              const float* __restrict__ mn, const float* __restrict__ vr,
              double* __restrict__ xo)
{
    __shared__ float wl[64 * 64];
    __shared__ float xl[4 * 64];
    int tid = threadIdx.x;
#pragma unroll
    for (int i = 0; i < 16; i++) wl[tid + 256 * i] = w1[tid + 256 * i];
    int row0 = blockIdx.x * 4;
    xl[tid] = x[(size_t)row0 * 64 + tid];
    __syncthreads();
    int o = tid & 63, r = tid >> 6;
    double acc = 0.0;
#pragma unroll
    for (int w = 0; w < 64; w++)
        acc = fma((double)xl[r * 64 + w], (double)wl[w * 64 + o], acc);
    double y = (acc - (double)mn[o]) * (1.0 / sqrt((double)vr[o] + 1e-5)) * (double)sc[o]
             + (double)bi[o];
    xo[(size_t)(row0 + r) * 64 + o] = y;
}

// ---------------------------------------------------------------------------
// Kernel 2/4: HLIF scan over T per (b,c). Reads f64 xbuf.
// ---------------------------------------------------------------------------
__global__ void hlif(const double* __restrict__ xin, float* __restrict__ spk,
                     const float* __restrict__ vth_raw, const float* __restrict__ dec_raw,
                     int C)
{
    int idx = blockIdx.x * blockDim.x + threadIdx.x;
    int b = idx / C, c = idx - b * C;
    double vth = softplus_d((double)vth_raw[c]) + 0.5;
    double dec = sigmoid_d((double)dec_raw[c] + 2.0);
    dec = fmin(fmax(dec, 0.0), 0.99);
    const double* xp = xin + (size_t)b * T_ * C + c;
    float* sp = spk + (size_t)b * T_ * C + c;
    double v = 0.0;
    for (int t = 0; t < T_; t += 8) {
        double xv[8];
#pragma unroll
        for (int u = 0; u < 8; u++) xv[u] = xp[(size_t)(t + u) * C];
#pragma unroll
        for (int u = 0; u < 8; u++) {
            v = v * dec + xv[u];
            double s = (v - vth > 0.0) ? 1.0 : 0.0;
            v -= s * vth;
            sp[(size_t)(t + u) * C] = (float)s;
        }
    }
}

// ---------------------------------------------------------------------------
// XCD-locality block swizzle for conv2's 128b x 30tt grid (3840 blocks).
// ---------------------------------------------------------------------------
__device__ __forceinline__ void swz_b_tt(int j, int& bb, int& tt) {
    int xcd = j & 7, slot = j >> 3;       // slot in [0,480)
    bb = xcd + 8 * (slot / 30);           // 16 b's per XCD
    tt = slot % 30;
}

// ---------------------------------------------------------------------------
// Kernel 3: conv2 (K=32, dil=4, pad 62, Cin=64, Cout=128) + bn2 -> xbuf (f64)
// (byte-identical to round-8 passing version)
// ---------------------------------------------------------------------------
__global__ __launch_bounds__(256)
void conv2_bn(const float* __restrict__ spk1, const float* __restrict__ w2,
              const float* __restrict__ sc, const float* __restrict__ bi,
              const float* __restrict__ mn, const float* __restrict__ vr,
              double* __restrict__ xo)
{
    __shared__ float S[140 * 64];   // rows t0-62 .. t0+15+62
    int tid = threadIdx.x;
    int bb, tt;
    swz_b_tt(blockIdx.x, bb, tt);
    int t0 = tt * 16;
    const float* sb = spk1 + (size_t)bb * T_ * 64;
    for (int i = tid; i < 140 * 64; i += 256) {
        int rr = i >> 6, cc = i & 63;
        int t = t0 - 62 + rr;
        S[i] = (t >= 0 && t < T_) ? sb[(size_t)t * 64 + cc] : 0.0f;
    }
    __syncthreads();
    int o = tid & 127, th = tid >> 7;
    double acc[8];
#pragma unroll
    for (int j = 0; j < 8; j++) acc[j] = 0.0;

    for (int k = 0; k < 32; k++) {
        int rbase = th * 8 + 4 * k;   // row for (j) = rbase + j
        const float* wp = w2 + (size_t)k * 64 * 128 + o;
        float p[8];
#pragma unroll
        for (int j = 0; j < 8; j++) p[j] = 0.0f;
        for (int cc = 0; cc < 64; cc += 4) {
            float4 sv[8];
#pragma unroll
            for (int j = 0; j < 8; j++)
                sv[j] = *(const float4*)&S[(rbase + j) * 64 + cc];
#pragma unroll
            for (int q = 0; q < 4; q++) {
                float w = wp[(size_t)(cc + q) * 128];
#pragma unroll
                for (int j = 0; j < 8; j++)
                    p[j] = fmaf(((const float*)&sv[j])[q], w, p[j]);
            }
        }
#pragma unroll
        for (int j = 0; j < 8; j++) acc[j] += (double)p[j];
    }
    double m = (double)mn[o], rs = 1.0 / sqrt((double)vr[o] + 1e-5);
    double s_ = (double)sc[o], b_ = (double)bi[o];
    double* xop = xo + ((size_t)bb * T_ + t0 + th * 8) * 128 + o;
#pragma unroll
    for (int j = 0; j < 8; j++) xop[(size_t)j * 128] = (acc[j] - m) * rs * s_ + b_;
}

// ---------------------------------------------------------------------------
// Kernel Pa: per-output-channel max |w3| -> scale exponents.
// recon[o] = 2^(e-30) (exact power of two), qscale[o] = 2^(30-e).
// ---------------------------------------------------------------------------
__global__ __launch_bounds__(64)
void prep_scale(const float* __restrict__ w3, double* __restrict__ recon,
                double* __restrict__ qscale)
{
    __shared__ float red[64];
    int o = blockIdx.x, l = threadIdx.x;
    float mx = 0.0f;
    for (int i = l; i < 4096; i += 64)
        mx = fmaxf(mx, fabsf(w3[(size_t)i * 128 + o]));
    red[l] = mx;
    __syncthreads();
    for (int s = 32; s > 0; s >>= 1) {
        if (l < s) red[l] = fmaxf(red[l], red[l + s]);
        __syncthreads();
    }
    if (l == 0) {
        float m = red[0];
        int e = (m > 0.0f) ? (ilogbf(m) + 1) : 0;
        recon[o]  = ldexp(1.0, e - 30);
        qscale[o] = ldexp(1.0, 30 - e);
    }
}

// ---------------------------------------------------------------------------
// Kernel Pb: quantize w3 to 31-bit fixed point, split into 4 exact signed-byte
// digit planes, packed in i8-MFMA B-fragment order.
// Slot map: grp = (k*2+cb)*8+nt; lane l: o = nt*16+(l&15),
// channels c = cb*64 + (l>>4)*16 + e (e=0..15) — identical map used by A-read.
// Layout: wq[((grp*4 + plane)*64 + l)*16 + e]. Total 2 MB.
// ---------------------------------------------------------------------------
__global__ __launch_bounds__(256)
void prep_quant(const float* __restrict__ w3, const double* __restrict__ qscale,
                char* __restrict__ wq)
{
    int id = blockIdx.x * 256 + threadIdx.x;   // 32768 total
    int l = id & 63;
    int grp = id >> 6;                         // 512 grps
    int nt = grp & 7;
    int kc = grp >> 3;                         // k*2+cb
    int cb = kc & 1, k = kc >> 1;
    int o = nt * 16 + (l & 15);
    int c0 = cb * 64 + (l >> 4) * 16;
    double qs = qscale[o];

    unsigned int pw[4][4];
#pragma unroll
    for (int p = 0; p < 4; p++)
#pragma unroll
        for (int wq4 = 0; wq4 < 4; wq4++) pw[p][wq4] = 0u;

#pragma unroll
    for (int e = 0; e < 16; e++) {
        float w = w3[((size_t)k * 128 + c0 + e) * 128 + o];
        int q = __double2int_rn((double)w * qs);
        int d0 = (int)(signed char)(q & 0xff); q = (q - d0) >> 8;
        int d1 = (int)(signed char)(q & 0xff); q = (q - d1) >> 8;
        int d2 = (int)(signed char)(q & 0xff); q = (q - d2) >> 8;
        int d3 = q;                            // |d3| <= 64
        int sh = (e & 3) * 8, wi = e >> 2;
        pw[0][wi] |= ((unsigned)d0 & 0xffu) << sh;
        pw[1][wi] |= ((unsigned)d1 & 0xffu) << sh;
        pw[2][wi] |= ((unsigned)d2 & 0xffu) << sh;
        pw[3][wi] |= ((unsigned)d3 & 0xffu) << sh;
    }
#pragma unroll
    for (int p = 0; p < 4; p++) {
        uint4* dst = (uint4*)(wq + (((size_t)grp * 4 + p) * 64 + l) * 16);
        uint4 v; v.x = pw[p][0]; v.y = pw[p][1]; v.z = pw[p][2]; v.w = pw[p][3];
        *dst = v;
    }
}

// ---------------------------------------------------------------------------
// Kernel 5: conv3 via EXACT i8 MFMA. Residue-class window (80 i8 rows, stride
// 144 B). Per block: 4 waves x (3 M-tiles x 2 N-tiles), K = 32 taps x 2
// 64-chan chunks, 4 digit planes, mfma_i32_16x16x64_i8 — i32 accumulation is
// exact, no merges needed. Recombine digits in int64 (exact), scale by
// power-of-two recon (exact), BN in f64 -> f64 xbuf.
// ---------------------------------------------------------------------------
__global__ __launch_bounds__(256)
void conv3_mfma(const float* __restrict__ spk2, const char* __restrict__ wq,
                const double* __restrict__ recon,
                const float* __restrict__ sc, const float* __restrict__ bi,
                const float* __restrict__ mn, const float* __restrict__ vr,
                double* __restrict__ xo)
{
    __shared__ __align__(16) char S[80 * 144];   // 11.25 KB
    int tid = threadIdx.x;
    int jj = blockIdx.x;               // grid 1536 = 8 xcd * (16 b * 12 rho)
    int xcd = jj & 7, slot = jj >> 3;
    int bb = xcd + 8 * (slot / 12);
    int rho = slot % 12;
    int rhop = (rho < 6) ? rho + 6 : rho - 6;
    int koff = (rho < 6) ? 0 : 1;
    const float* sb = spk2 + (size_t)bb * T_ * 128;

    // stage: window row w holds class row w-16 as i8 (exact 0/1)
    for (int i = tid; i < 80 * 128; i += 256) {
        int w = i >> 7, c = i & 127;
        float v = (w >= 16 && w < 56) ? sb[(size_t)(12 * (w - 16) + rhop) * 128 + c] : 0.0f;
        S[w * 144 + c] = (char)v;
    }
    __syncthreads();

    int l = tid & 63, wv = tid >> 6;
    int lm = l & 15, lg = l >> 4;
    const char* arow = S + (lm + koff) * 144 + lg * 16;

    i32x4 acc[3][2][4];
#pragma unroll
    for (int mt = 0; mt < 3; mt++)
#pragma unroll
        for (int nt = 0; nt < 2; nt++)
#pragma unroll
            for (int p = 0; p < 4; p++) acc[mt][nt][p] = (i32x4)(0);

    for (int k = 0; k < 32; k++) {
        const char* ap = arow + k * 144;
#pragma unroll
        for (int cb = 0; cb < 2; cb++) {
            i32x4 A0 = *(const i32x4*)(ap + cb * 64);
            i32x4 A1 = *(const i32x4*)(ap + cb * 64 + 16 * 144);
            i32x4 A2 = *(const i32x4*)(ap + cb * 64 + 32 * 144);
            const char* bp = wq + ((((size_t)(k * 2 + cb) * 8 + wv * 2) * 4) * 64 + l) * 16;
#pragma unroll
            for (int p = 0; p < 4; p++) {
                i32x4 B0 = *(const i32x4*)(bp + p * 1024);
                i32x4 B1 = *(const i32x4*)(bp + 4096 + p * 1024);
                acc[0][0][p] = __builtin_amdgcn_mfma_i32_16x16x64_i8(A0, B0, acc[0][0][p], 0, 0, 0);
                acc[1][0][p] = __builtin_amdgcn_mfma_i32_16x16x64_i8(A1, B0, acc[1][0][p], 0, 0, 0);
                acc[2][0][p] = __builtin_amdgcn_mfma_i32_16x16x64_i8(A2, B0, acc[2][0][p], 0, 0, 0);
                acc[0][1][p] = __builtin_amdgcn_mfma_i32_16x16x64_i8(A0, B1, acc[0][1][p], 0, 0, 0);
                acc[1][1][p] = __builtin_amdgcn_mfma_i32_16x16x64_i8(A1, B1, acc[1][1][p], 0, 0, 0);
                acc[2][1][p] = __builtin_amdgcn_mfma_i32_16x16x64_i8(A2, B1, acc[2][1][p], 0, 0, 0);
            }
        }
    }

#pragma unroll
    for (int nt = 0; nt < 2; nt++) {
        int o = wv * 32 + nt * 16 + lm;
        double rc = recon[o];
        double m_ = (double)mn[o], rs_ = 1.0 / sqrt((double)vr[o] + 1e-5);
        double s_ = (double)sc[o], b_ = (double)bi[o];
#pragma unroll
        for (int mt = 0; mt < 3; mt++)
#pragma unroll
            for (int rg = 0; rg < 4; rg++) {
                int mo = mt * 16 + lg * 4 + rg;
                if (mo < 40) {
                    long long D = (long long)acc[mt][nt][0][rg]
                                + ((long long)acc[mt][nt][1][rg] << 8)
                                + ((long long)acc[mt][nt][2][rg] << 16)
                                + ((long long)acc[mt][nt][3][rg] << 24);
                    double val = (double)D * rc;      // exact: sum of s * w_q
                    int t_out = 12 * mo + rho;
                    xo[((size_t)bb * T_ + t_out) * 128 + o] =
                        (val - m_) * rs_ * s_ + b_;
                }
            }
    }
}

// ---------------------------------------------------------------------------
// Kernel 6: ALIF scan per (b,c), C=128. Reads f64 xbuf (round-8 version).
// ---------------------------------------------------------------------------
__global__ void alif(const double* __restrict__ xin, float* __restrict__ spk)
{
    int idx = blockIdx.x * blockDim.x + threadIdx.x;
    int b = idx >> 7, c = idx & 127;
    const double* xp = xin + (size_t)b * T_ * 128 + c;
    float* sp = spk + (size_t)b * T_ * 128 + c;
    double v = 0.0, th = 0.0, ps = 0.0;
    const double dd = 0.9, adp = 0.9, beta = 1.8;
    for (int t = 0; t < T_; t += 8) {
        double xv[8];
#pragma unroll
        for (int u = 0; u < 8; u++) xv[u] = xp[(size_t)(t + u) * 128];
#pragma unroll
        for (int u = 0; u < 8; u++) {
            th = th * adp + ps * beta;
            v = v * dd + xv[u];
            double vth = 0.5 + th;
            double s = (v - vth > 0.0) ? 1.0 : 0.0;
            v -= s * vth;
            ps = s;
            sp[(size_t)(t + u) * 128] = (float)s;
        }
    }
}

// ---------------------------------------------------------------------------
// Kernel 7: readout — dense + LI scan + dp + attention + logits. 1 block per b.
// ---------------------------------------------------------------------------
__global__ __launch_bounds__(256)
void readout(const float* __restrict__ spk3, const float* __restrict__ dw,
             const float* __restrict__ db, const float* __restrict__ a1w,
             const float* __restrict__ a1b, const float* __restrict__ a2w,
             const float* __restrict__ a2b, float* __restrict__ out)
{
    __shared__ double dl[480 * 4];
    __shared__ double dp[20 * 4];
    __shared__ double zl[20];
    __shared__ double red[1];
    int b = blockIdx.x, tid = threadIdx.x;
    const float* sp = spk3 + (size_t)b * T_ * 128;

    for (int i = tid; i < 1920; i += 256) {
        int t = i >> 2, j = i & 3;
        const float* row = sp + (size_t)t * 128;
        double acc = 0.0;
        for (int c = 0; c < 128; c++)
            acc = fma((double)row[c], (double)dw[c * 4 + j], acc);
        dl[i] = acc + (double)db[j];
    }
    __syncthreads();
    if (tid < 4) {
        const double dec = 0.9, om = 1.0 - 0.9;
        double v = 0.0;
        for (int t = 0; t < T_; t++) {
            v = v * dec + dl[t * 4 + tid] * om;
            dl[t * 4 + tid] = v;
        }
    }
    __syncthreads();
    if (tid < 80) {
        int g = tid >> 2, j = tid & 3;
        double s1 = 0.0, s2 = 0.0;
        for (int u = 0; u < 12; u++) {
            s1 += dl[(g * 24 + u) * 4 + j];
            s2 += dl[(g * 24 + 12 + u) * 4 + j];
        }
        dp[g * 4 + j] = s2 / 12.0 - s1 / 12.0;
    }
    __syncthreads();
    if (tid < 20) {
        int g = tid;
        double z = (double)a2b[0];
        for (int i = 0; i < 8; i++) {
            double h = (double)a1b[i];
            for (int j = 0; j < 4; j++)
                h = fma(dp[g * 4 + j], (double)a1w[j * 8 + i], h);
            h = fmax(h, 0.0);
            z = fma(h, (double)a2w[i], z);
        }
        zl[g] = z;
    }
    __syncthreads();
    if (tid == 0) {
        double m = zl[0];
        for (int g = 1; g < 20; g++) m = fmax(m, zl[g]);
        double s = 0.0;
        for (int g = 0; g < 20; g++) { zl[g] = exp(zl[g] - m); s += zl[g]; }
        red[0] = s;
    }
    __syncthreads();
    if (tid < 4) {
        double s = red[0];
        double acc = 0.0;
        for (int g = 0; g < 20; g++) acc += dp[g * 4 + tid] * (zl[g] / s);
        out[b * 4 + tid] = (float)acc;
    }
}

// ---------------------------------------------------------------------------
extern "C" void kernel_launch(void* const* d_in, const int* in_sizes, int n_in,
                              void* d_out, int out_size, void* d_ws, size_t ws_size,
                              hipStream_t stream)
{
    const float* x     = (const float*)d_in[0];
    const float* w1    = (const float*)d_in[1];
    const float* bn1s  = (const float*)d_in[2];
    const float* bn1b  = (const float*)d_in[3];
    const float* bn1m  = (const float*)d_in[4];
    const float* bn1v  = (const float*)d_in[5];
    const float* vth1  = (const float*)d_in[6];
    const float* dec1  = (const float*)d_in[7];
    const float* w2    = (const float*)d_in[8];
    const float* bn2s  = (const float*)d_in[9];
    const float* bn2b  = (const float*)d_in[10];
    const float* bn2m  = (const float*)d_in[11];
    const float* bn2v  = (const float*)d_in[12];
    const float* vth2  = (const float*)d_in[13];
    const float* dec2  = (const float*)d_in[14];
    const float* w3    = (const float*)d_in[15];
    const float* bn3s  = (const float*)d_in[16];
    const float* bn3b  = (const float*)d_in[17];
    const float* bn3m  = (const float*)d_in[18];
    const float* bn3v  = (const float*)d_in[19];
    const float* dw    = (const float*)d_in[20];
    const float* db    = (const float*)d_in[21];
    const float* a1w   = (const float*)d_in[22];
    const float* a1b   = (const float*)d_in[23];
    const float* a2w   = (const float*)d_in[24];
    const float* a2b   = (const float*)d_in[25];

    float* out = (float*)d_out;
    double* xbuf = (double*)d_ws;                         // 61440*128 doubles = 62.9 MB

    // Digit planes + scales staged in the spk3 output slot: written by prep,
    // consumed by conv3_mfma, overwritten afterwards by alif (stream-ordered).
    char*   wq     = (char*)(out + OUT_SPK3);             // 2 MB
    double* recon  = (double*)(wq + (2 << 20));           // 128 doubles
    double* qscale = recon + 128;                         // 128 doubles

    // Stage 1
    conv1_bn<<<BT_ / 4, 256, 0, stream>>>(x, w1, bn1s, bn1b, bn1m, bn1v, xbuf);
    hlif<<<(B_ * 64) / 256, 256, 0, stream>>>(xbuf, out + OUT_SPK1, vth1, dec1, 64);
    // Stage 2
    conv2_bn<<<B_ * 30, 256, 0, stream>>>(out + OUT_SPK1, w2, bn2s, bn2b, bn2m, bn2v, xbuf);
    hlif<<<(B_ * 128) / 256, 256, 0, stream>>>(xbuf, out + OUT_SPK2, vth2, dec2, 128);
    // Stage 3: exact i8 fixed-point MFMA
    prep_scale<<<128, 64, 0, stream>>>(w3, recon, qscale);
    prep_quant<<<128, 256, 0, stream>>>(w3, qscale, wq);
    conv3_mfma<<<B_ * 12, 256, 0, stream>>>(out + OUT_SPK2, wq, recon,
                                            bn3s, bn3b, bn3m, bn3v, xbuf);
    alif<<<(B_ * 128) / 256, 256, 0, stream>>>(xbuf, out + OUT_SPK3);
    // Readout
    readout<<<B_, 256, 0, stream>>>(out + OUT_SPK3, dw, db, a1w, a1b, a2w, a2b, out);
}

// Round 11
// 737.342 us; speedup vs baseline: 19.1416x; 1.5492x over previous
//
#include <hip/hip_runtime.h>
#include <cmath>

#define B_ 128
#define T_ 480
#define BT_ 61440

// output layout (fp32 elements)
#define OUT_SPK1 512
#define OUT_SPK2 3932672
#define OUT_SPK3 11796992

typedef __attribute__((ext_vector_type(4))) int i32x4;

__device__ __forceinline__ double softplus_d(double x) {
    return (x > 0.0) ? (x + log1p(exp(-x))) : log1p(exp(x));
}
__device__ __forceinline__ double sigmoid_d(double x) {
    return 1.0 / (1.0 + exp(-x));
}

// ---------------------------------------------------------------------------
// Kernel 1: conv1 (61440x64 @ 64x64) + bn1 -> xbuf (f64).
// ---------------------------------------------------------------------------
__global__ __launch_bounds__(256)
void conv1_bn(const float* __restrict__ x, const float* __restrict__ w1,
              const float* __restrict__ sc, const float* __restrict__ bi,
              const float* __restrict__ mn, const float* __restrict__ vr,
              double* __restrict__ xo)
{
    __shared__ float wl[64 * 64];
    __shared__ float xl[4 * 64];
    int tid = threadIdx.x;
#pragma unroll
    for (int i = 0; i < 16; i++) wl[tid + 256 * i] = w1[tid + 256 * i];
    int row0 = blockIdx.x * 4;
    xl[tid] = x[(size_t)row0 * 64 + tid];
    __syncthreads();
    int o = tid & 63, r = tid >> 6;
    double acc = 0.0;
#pragma unroll
    for (int w = 0; w < 64; w++)
        acc = fma((double)xl[r * 64 + w], (double)wl[w * 64 + o], acc);
    double y = (acc - (double)mn[o]) * (1.0 / sqrt((double)vr[o] + 1e-5)) * (double)sc[o]
             + (double)bi[o];
    xo[(size_t)(row0 + r) * 64 + o] = y;
}

// ---------------------------------------------------------------------------
// Kernel 2/4: HLIF scan over T per (b,c). Reads f64 xbuf.
// ---------------------------------------------------------------------------
__global__ void hlif(const double* __restrict__ xin, float* __restrict__ spk,
                     const float* __restrict__ vth_raw, const float* __restrict__ dec_raw,
                     int C)
{
    int idx = blockIdx.x * blockDim.x + threadIdx.x;
    int b = idx / C, c = idx - b * C;
    double vth = softplus_d((double)vth_raw[c]) + 0.5;
    double dec = sigmoid_d((double)dec_raw[c] + 2.0);
    dec = fmin(fmax(dec, 0.0), 0.99);
    const double* xp = xin + (size_t)b * T_ * C + c;
    float* sp = spk + (size_t)b * T_ * C + c;
    double v = 0.0;
    for (int t = 0; t < T_; t += 8) {
        double xv[8];
#pragma unroll
        for (int u = 0; u < 8; u++) xv[u] = xp[(size_t)(t + u) * C];
#pragma unroll
        for (int u = 0; u < 8; u++) {
            v = v * dec + xv[u];
            double s = (v - vth > 0.0) ? 1.0 : 0.0;
            v -= s * vth;
            sp[(size_t)(t + u) * C] = (float)s;
        }
    }
}

// ---------------------------------------------------------------------------
// Kernel Pa (generic): per-output-channel max |w| -> scale exponents.
// recon[o] = 2^(e-30) (exact), qscale[o] = 2^(30-e). K = chan count.
// ---------------------------------------------------------------------------
__global__ __launch_bounds__(64)
void prep_scale(const float* __restrict__ w, int K, double* __restrict__ recon,
                double* __restrict__ qscale)
{
    __shared__ float red[64];
    int o = blockIdx.x, l = threadIdx.x;
    float mx = 0.0f;
    for (int i = l; i < K; i += 64)
        mx = fmaxf(mx, fabsf(w[(size_t)i * 128 + o]));
    red[l] = mx;
    __syncthreads();
    for (int s = 32; s > 0; s >>= 1) {
        if (l < s) red[l] = fmaxf(red[l], red[l + s]);
        __syncthreads();
    }
    if (l == 0) {
        float m = red[0];
        int e = (m > 0.0f) ? (ilogbf(m) + 1) : 0;
        recon[o]  = ldexp(1.0, e - 30);
        qscale[o] = ldexp(1.0, 30 - e);
    }
}

// ---------------------------------------------------------------------------
// Kernel Pb3: quantize w3 -> 4 signed-byte digit planes, i8-B-fragment order.
// grp = (k*2+cb)*8+nt; lane l: o = nt*16+(l&15), c = cb*64+(l>>4)*16+e.
// ---------------------------------------------------------------------------
__global__ __launch_bounds__(256)
void prep_quant3(const float* __restrict__ w3, const double* __restrict__ qscale,
                 char* __restrict__ wq)
{
    int id = blockIdx.x * 256 + threadIdx.x;   // 32768 total
    int l = id & 63;
    int grp = id >> 6;                         // 512 grps
    int nt = grp & 7;
    int kc = grp >> 3;
    int cb = kc & 1, k = kc >> 1;
    int o = nt * 16 + (l & 15);
    int c0 = cb * 64 + (l >> 4) * 16;
    double qs = qscale[o];

    unsigned int pw[4][4];
#pragma unroll
    for (int p = 0; p < 4; p++)
#pragma unroll
        for (int wi = 0; wi < 4; wi++) pw[p][wi] = 0u;

#pragma unroll
    for (int e = 0; e < 16; e++) {
        float w = w3[((size_t)k * 128 + c0 + e) * 128 + o];
        int q = __double2int_rn((double)w * qs);
        int d0 = (int)(signed char)(q & 0xff); q = (q - d0) >> 8;
        int d1 = (int)(signed char)(q & 0xff); q = (q - d1) >> 8;
        int d2 = (int)(signed char)(q & 0xff); q = (q - d2) >> 8;
        int d3 = q;
        int sh = (e & 3) * 8, wi = e >> 2;
        pw[0][wi] |= ((unsigned)d0 & 0xffu) << sh;
        pw[1][wi] |= ((unsigned)d1 & 0xffu) << sh;
        pw[2][wi] |= ((unsigned)d2 & 0xffu) << sh;
        pw[3][wi] |= ((unsigned)d3 & 0xffu) << sh;
    }
#pragma unroll
    for (int p = 0; p < 4; p++) {
        uint4* dst = (uint4*)(wq + (((size_t)grp * 4 + p) * 64 + l) * 16);
        uint4 v; v.x = pw[p][0]; v.y = pw[p][1]; v.z = pw[p][2]; v.w = pw[p][3];
        *dst = v;
    }
}

// ---------------------------------------------------------------------------
// Kernel Pb2: quantize w2 (32,64,128) -> digit planes, grp = k*8+nt (Cin=64 =
// one K=64 chunk): lane l: o = nt*16+(l&15), c = (l>>4)*16+e. 1 MB.
// ---------------------------------------------------------------------------
__global__ __launch_bounds__(256)
void prep_quant2(const float* __restrict__ w2, const double* __restrict__ qscale,
                 char* __restrict__ wq)
{
    int id = blockIdx.x * 256 + threadIdx.x;   // 16384 total
    int l = id & 63;
    int grp = id >> 6;                         // 256 grps
    int nt = grp & 7;
    int k = grp >> 3;
    int o = nt * 16 + (l & 15);
    int c0 = (l >> 4) * 16;
    double qs = qscale[o];

    unsigned int pw[4][4];
#pragma unroll
    for (int p = 0; p < 4; p++)
#pragma unroll
        for (int wi = 0; wi < 4; wi++) pw[p][wi] = 0u;

#pragma unroll
    for (int e = 0; e < 16; e++) {
        float w = w2[((size_t)k * 64 + c0 + e) * 128 + o];
        int q = __double2int_rn((double)w * qs);
        int d0 = (int)(signed char)(q & 0xff); q = (q - d0) >> 8;
        int d1 = (int)(signed char)(q & 0xff); q = (q - d1) >> 8;
        int d2 = (int)(signed char)(q & 0xff); q = (q - d2) >> 8;
        int d3 = q;
        int sh = (e & 3) * 8, wi = e >> 2;
        pw[0][wi] |= ((unsigned)d0 & 0xffu) << sh;
        pw[1][wi] |= ((unsigned)d1 & 0xffu) << sh;
        pw[2][wi] |= ((unsigned)d2 & 0xffu) << sh;
        pw[3][wi] |= ((unsigned)d3 & 0xffu) << sh;
    }
#pragma unroll
    for (int p = 0; p < 4; p++) {
        uint4* dst = (uint4*)(wq + (((size_t)grp * 4 + p) * 64 + l) * 16);
        uint4 v; v.x = pw[p][0]; v.y = pw[p][1]; v.z = pw[p][2]; v.w = pw[p][3];
        *dst = v;
    }
}

// ---------------------------------------------------------------------------
// Kernel 3: conv2 via EXACT i8 MFMA. Residue classes mod 4: t=4a+rho reads
// class rho'=(rho+2)&3 at m=a+k+m0, m0 = -16 (rho<2) else -15. Per (b,rho):
// dil-1 K=32 conv over 120 class rows (padded to 128). Window 160 rows x 64ch
// i8 in LDS (stride 80B: 16-aligned, bank-period 8 -> 2-way free). 8 waves,
// wave = 4 M-tiles x 2 N-tiles x 4 planes; K=64 = whole Cin per tap.
// i32 accum exact; int64 recombine; power-of-two scale; BN f64 -> f64 xbuf.
// ---------------------------------------------------------------------------
__global__ __launch_bounds__(512)
void conv2_mfma(const float* __restrict__ spk1, const char* __restrict__ wq,
                const double* __restrict__ recon,
                const float* __restrict__ sc, const float* __restrict__ bi,
                const float* __restrict__ mn, const float* __restrict__ vr,
                double* __restrict__ xo)
{
    __shared__ __align__(16) char S[160 * 80];   // 12.8 KB
    int tid = threadIdx.x;
    int jj = blockIdx.x;                 // 512 = 8 xcd * (16 b * 4 rho)
    int xcd = jj & 7, slot = jj >> 3;    // slot in [0,64)
    int bb = xcd + 8 * (slot >> 2);
    int rho = slot & 3;
    int rhop = (rho + 2) & 3;
    int m0 = (rho < 2) ? -16 : -15;
    const float* sb = spk1 + (size_t)bb * T_ * 64;

    for (int i = tid; i < 160 * 64; i += 512) {
        int widx = i >> 6, c = i & 63;
        int m = widx + m0;
        float v = ((unsigned)m < 120u) ? sb[(size_t)(4 * m + rhop) * 64 + c] : 0.0f;
        S[widx * 80 + c] = (char)v;
    }
    __syncthreads();

    int l = tid & 63, wv = tid >> 6;
    int wm = wv >> 2, wn = wv & 3;       // M-half, N-quarter
    int lm = l & 15, lg = l >> 4;

    i32x4 acc[4][2][4];
#pragma unroll
    for (int mt = 0; mt < 4; mt++)
#pragma unroll
        for (int nt = 0; nt < 2; nt++)
#pragma unroll
            for (int p = 0; p < 4; p++) acc[mt][nt][p] = (i32x4)(0);

    const char* arow0 = S + (wm * 64 + lm) * 80 + lg * 16;
    for (int k = 0; k < 32; k++) {
        const char* ap = arow0 + k * 80;
        i32x4 A0 = *(const i32x4*)(ap);
        i32x4 A1 = *(const i32x4*)(ap + 16 * 80);
        i32x4 A2 = *(const i32x4*)(ap + 32 * 80);
        i32x4 A3 = *(const i32x4*)(ap + 48 * 80);
        const char* bp = wq + (((size_t)(k * 8 + wn * 2) * 4) * 64 + l) * 16;
#pragma unroll
        for (int p = 0; p < 4; p++) {
            i32x4 B0 = *(const i32x4*)(bp + p * 1024);
            i32x4 B1 = *(const i32x4*)(bp + 4096 + p * 1024);
            acc[0][0][p] = __builtin_amdgcn_mfma_i32_16x16x64_i8(A0, B0, acc[0][0][p], 0, 0, 0);
            acc[1][0][p] = __builtin_amdgcn_mfma_i32_16x16x64_i8(A1, B0, acc[1][0][p], 0, 0, 0);
            acc[2][0][p] = __builtin_amdgcn_mfma_i32_16x16x64_i8(A2, B0, acc[2][0][p], 0, 0, 0);
            acc[3][0][p] = __builtin_amdgcn_mfma_i32_16x16x64_i8(A3, B0, acc[3][0][p], 0, 0, 0);
            acc[0][1][p] = __builtin_amdgcn_mfma_i32_16x16x64_i8(A0, B1, acc[0][1][p], 0, 0, 0);
            acc[1][1][p] = __builtin_amdgcn_mfma_i32_16x16x64_i8(A1, B1, acc[1][1][p], 0, 0, 0);
            acc[2][1][p] = __builtin_amdgcn_mfma_i32_16x16x64_i8(A2, B1, acc[2][1][p], 0, 0, 0);
            acc[3][1][p] = __builtin_amdgcn_mfma_i32_16x16x64_i8(A3, B1, acc[3][1][p], 0, 0, 0);
        }
    }

#pragma unroll
    for (int nt = 0; nt < 2; nt++) {
        int o = (wn * 2 + nt) * 16 + lm;
        double rc = recon[o];
        double m_ = (double)mn[o], rs_ = 1.0 / sqrt((double)vr[o] + 1e-5);
        double s_ = (double)sc[o], b_ = (double)bi[o];
#pragma unroll
        for (int mt = 0; mt < 4; mt++)
#pragma unroll
            for (int rg = 0; rg < 4; rg++) {
                int a = (wm * 4 + mt) * 16 + lg * 4 + rg;
                if (a < 120) {
                    long long D = (long long)acc[mt][nt][0][rg]
                                + ((long long)acc[mt][nt][1][rg] << 8)
                                + ((long long)acc[mt][nt][2][rg] << 16)
                                + ((long long)acc[mt][nt][3][rg] << 24);
                    double val = (double)D * rc;
                    int t_out = 4 * a + rho;
                    xo[((size_t)bb * T_ + t_out) * 128 + o] =
                        (val - m_) * rs_ * s_ + b_;
                }
            }
    }
}

// ---------------------------------------------------------------------------
// Kernel 5: conv3 via EXACT i8 MFMA (round-10 passing version, unchanged).
// ---------------------------------------------------------------------------
__global__ __launch_bounds__(256)
void conv3_mfma(const float* __restrict__ spk2, const char* __restrict__ wq,
                const double* __restrict__ recon,
                const float* __restrict__ sc, const float* __restrict__ bi,
                const float* __restrict__ mn, const float* __restrict__ vr,
                double* __restrict__ xo)
{
    __shared__ __align__(16) char S[80 * 144];   // 11.25 KB
    int tid = threadIdx.x;
    int jj = blockIdx.x;               // grid 1536 = 8 xcd * (16 b * 12 rho)
    int xcd = jj & 7, slot = jj >> 3;
    int bb = xcd + 8 * (slot / 12);
    int rho = slot % 12;
    int rhop = (rho < 6) ? rho + 6 : rho - 6;
    int koff = (rho < 6) ? 0 : 1;
    const float* sb = spk2 + (size_t)bb * T_ * 128;

    for (int i = tid; i < 80 * 128; i += 256) {
        int w = i >> 7, c = i & 127;
        float v = (w >= 16 && w < 56) ? sb[(size_t)(12 * (w - 16) + rhop) * 128 + c] : 0.0f;
        S[w * 144 + c] = (char)v;
    }
    __syncthreads();

    int l = tid & 63, wv = tid >> 6;
    int lm = l & 15, lg = l >> 4;
    const char* arow = S + (lm + koff) * 144 + lg * 16;

    i32x4 acc[3][2][4];
#pragma unroll
    for (int mt = 0; mt < 3; mt++)
#pragma unroll
        for (int nt = 0; nt < 2; nt++)
#pragma unroll
            for (int p = 0; p < 4; p++) acc[mt][nt][p] = (i32x4)(0);

    for (int k = 0; k < 32; k++) {
        const char* ap = arow + k * 144;
#pragma unroll
        for (int cb = 0; cb < 2; cb++) {
            i32x4 A0 = *(const i32x4*)(ap + cb * 64);
            i32x4 A1 = *(const i32x4*)(ap + cb * 64 + 16 * 144);
            i32x4 A2 = *(const i32x4*)(ap + cb * 64 + 32 * 144);
            const char* bp = wq + ((((size_t)(k * 2 + cb) * 8 + wv * 2) * 4) * 64 + l) * 16;
#pragma unroll
            for (int p = 0; p < 4; p++) {
                i32x4 B0 = *(const i32x4*)(bp + p * 1024);
                i32x4 B1 = *(const i32x4*)(bp + 4096 + p * 1024);
                acc[0][0][p] = __builtin_amdgcn_mfma_i32_16x16x64_i8(A0, B0, acc[0][0][p], 0, 0, 0);
                acc[1][0][p] = __builtin_amdgcn_mfma_i32_16x16x64_i8(A1, B0, acc[1][0][p], 0, 0, 0);
                acc[2][0][p] = __builtin_amdgcn_mfma_i32_16x16x64_i8(A2, B0, acc[2][0][p], 0, 0, 0);
                acc[0][1][p] = __builtin_amdgcn_mfma_i32_16x16x64_i8(A0, B1, acc[0][1][p], 0, 0, 0);
                acc[1][1][p] = __builtin_amdgcn_mfma_i32_16x16x64_i8(A1, B1, acc[1][1][p], 0, 0, 0);
                acc[2][1][p] = __builtin_amdgcn_mfma_i32_16x16x64_i8(A2, B1, acc[2][1][p], 0, 0, 0);
            }
        }
    }

#pragma unroll
    for (int nt = 0; nt < 2; nt++) {
        int o = wv * 32 + nt * 16 + lm;
        double rc = recon[o];
        double m_ = (double)mn[o], rs_ = 1.0 / sqrt((double)vr[o] + 1e-5);
        double s_ = (double)sc[o], b_ = (double)bi[o];
#pragma unroll
        for (int mt = 0; mt < 3; mt++)
#pragma unroll
            for (int rg = 0; rg < 4; rg++) {
                int mo = mt * 16 + lg * 4 + rg;
                if (mo < 40) {
                    long long D = (long long)acc[mt][nt][0][rg]
                                + ((long long)acc[mt][nt][1][rg] << 8)
                                + ((long long)acc[mt][nt][2][rg] << 16)
                                + ((long long)acc[mt][nt][3][rg] << 24);
                    double val = (double)D * rc;
                    int t_out = 12 * mo + rho;
                    xo[((size_t)bb * T_ + t_out) * 128 + o] =
                        (val - m_) * rs_ * s_ + b_;
                }
            }
    }
}

// ---------------------------------------------------------------------------
// Kernel 6: ALIF scan per (b,c), C=128. Reads f64 xbuf.
// ---------------------------------------------------------------------------
__global__ void alif(const double* __restrict__ xin, float* __restrict__ spk)
{
    int idx = blockIdx.x * blockDim.x + threadIdx.x;
    int b = idx >> 7, c = idx & 127;
    const double* xp = xin + (size_t)b * T_ * 128 + c;
    float* sp = spk + (size_t)b * T_ * 128 + c;
    double v = 0.0, th = 0.0, ps = 0.0;
    const double dd = 0.9, adp = 0.9, beta = 1.8;
    for (int t = 0; t < T_; t += 8) {
        double xv[8];
#pragma unroll
        for (int u = 0; u < 8; u++) xv[u] = xp[(size_t)(t + u) * 128];
#pragma unroll
        for (int u = 0; u < 8; u++) {
            th = th * adp + ps * beta;
            v = v * dd + xv[u];
            double vth = 0.5 + th;
            double s = (v - vth > 0.0) ? 1.0 : 0.0;
            v -= s * vth;
            ps = s;
            sp[(size_t)(t + u) * 128] = (float)s;
        }
    }
}

// ---------------------------------------------------------------------------
// Kernel 7: readout — dense + LI scan + dp + attention + logits. 1 block per b.
// ---------------------------------------------------------------------------
__global__ __launch_bounds__(256)
void readout(const float* __restrict__ spk3, const float* __restrict__ dw,
             const float* __restrict__ db, const float* __restrict__ a1w,
             const float* __restrict__ a1b, const float* __restrict__ a2w,
             const float* __restrict__ a2b, float* __restrict__ out)
{
    __shared__ double dl[480 * 4];
    __shared__ double dp[20 * 4];
    __shared__ double zl[20];
    __shared__ double red[1];
    int b = blockIdx.x, tid = threadIdx.x;
    const float* sp = spk3 + (size_t)b * T_ * 128;

    for (int i = tid; i < 1920; i += 256) {
        int t = i >> 2, j = i & 3;
        const float* row = sp + (size_t)t * 128;
        double acc = 0.0;
        for (int c = 0; c < 128; c++)
            acc = fma((double)row[c], (double)dw[c * 4 + j], acc);
        dl[i] = acc + (double)db[j];
    }
    __syncthreads();
    if (tid < 4) {
        const double dec = 0.9, om = 1.0 - 0.9;
        double v = 0.0;
        for (int t = 0; t < T_; t++) {
            v = v * dec + dl[t * 4 + tid] * om;
            dl[t * 4 + tid] = v;
        }
    }
    __syncthreads();
    if (tid < 80) {
        int g = tid >> 2, j = tid & 3;
        double s1 = 0.0, s2 = 0.0;
        for (int u = 0; u < 12; u++) {
            s1 += dl[(g * 24 + u) * 4 + j];
            s2 += dl[(g * 24 + 12 + u) * 4 + j];
        }
        dp[g * 4 + j] = s2 / 12.0 - s1 / 12.0;
    }
    __syncthreads();
    if (tid < 20) {
        int g = tid;
        double z = (double)a2b[0];
        for (int i = 0; i < 8; i++) {
            double h = (double)a1b[i];
            for (int j = 0; j < 4; j++)
                h = fma(dp[g * 4 + j], (double)a1w[j * 8 + i], h);
            h = fmax(h, 0.0);
            z = fma(h, (double)a2w[i], z);
        }
        zl[g] = z;
    }
    __syncthreads();
    if (tid == 0) {
        double m = zl[0];
        for (int g = 1; g < 20; g++) m = fmax(m, zl[g]);
        double s = 0.0;
        for (int g = 0; g < 20; g++) { zl[g] = exp(zl[g] - m); s += zl[g]; }
        red[0] = s;
    }
    __syncthreads();
    if (tid < 4) {
        double s = red[0];
        double acc = 0.0;
        for (int g = 0; g < 20; g++) acc += dp[g * 4 + tid] * (zl[g] / s);
        out[b * 4 + tid] = (float)acc;
    }
}

// ---------------------------------------------------------------------------
extern "C" void kernel_launch(void* const* d_in, const int* in_sizes, int n_in,
                              void* d_out, int out_size, void* d_ws, size_t ws_size,
                              hipStream_t stream)
{
    const float* x     = (const float*)d_in[0];
    const float* w1    = (const float*)d_in[1];
    const float* bn1s  = (const float*)d_in[2];
    const float* bn1b  = (const float*)d_in[3];
    const float* bn1m  = (const float*)d_in[4];
    const float* bn1v  = (const float*)d_in[5];
    const float* vth1  = (const float*)d_in[6];
    const float* dec1  = (const float*)d_in[7];
    const float* w2    = (const float*)d_in[8];
    const float* bn2s  = (const float*)d_in[9];
    const float* bn2b  = (const float*)d_in[10];
    const float* bn2m  = (const float*)d_in[11];
    const float* bn2v  = (const float*)d_in[12];
    const float* vth2  = (const float*)d_in[13];
    const float* dec2  = (const float*)d_in[14];
    const float* w3    = (const float*)d_in[15];
    const float* bn3s  = (const float*)d_in[16];
    const float* bn3b  = (const float*)d_in[17];
    const float* bn3m  = (const float*)d_in[18];
    const float* bn3v  = (const float*)d_in[19];
    const float* dw    = (const float*)d_in[20];
    const float* db    = (const float*)d_in[21];
    const float* a1w   = (const float*)d_in[22];
    const float* a1b   = (const float*)d_in[23];
    const float* a2w   = (const float*)d_in[24];
    const float* a2b   = (const float*)d_in[25];

    float* out = (float*)d_out;
    double* xbuf = (double*)d_ws;                         // 61440*128 doubles = 62.9 MB

    // Staging in the spk3 output slot (31.5 MB): consumed before alif
    // overwrites it (stream-ordered).
    char*   base    = (char*)(out + OUT_SPK3);
    char*   wq3     = base;                               // 2 MB
    double* recon3  = (double*)(base + 0x200000);         // 128 d
    double* qscale3 = recon3 + 128;
    char*   wq2     = base + 0x200000 + 0x1000;           // 1 MB
    double* recon2  = (double*)(base + 0x300000 + 0x1000);
    double* qscale2 = recon2 + 128;

    // Stage 1
    conv1_bn<<<BT_ / 4, 256, 0, stream>>>(x, w1, bn1s, bn1b, bn1m, bn1v, xbuf);
    hlif<<<(B_ * 64) / 256, 256, 0, stream>>>(xbuf, out + OUT_SPK1, vth1, dec1, 64);
    // Stage 2: exact i8 fixed-point MFMA
    prep_scale<<<128, 64, 0, stream>>>(w2, 2048, recon2, qscale2);
    prep_quant2<<<64, 256, 0, stream>>>(w2, qscale2, wq2);
    conv2_mfma<<<B_ * 4, 512, 0, stream>>>(out + OUT_SPK1, wq2, recon2,
                                           bn2s, bn2b, bn2m, bn2v, xbuf);
    hlif<<<(B_ * 128) / 256, 256, 0, stream>>>(xbuf, out + OUT_SPK2, vth2, dec2, 128);
    // Stage 3: exact i8 fixed-point MFMA
    prep_scale<<<128, 64, 0, stream>>>(w3, 4096, recon3, qscale3);
    prep_quant3<<<128, 256, 0, stream>>>(w3, qscale3, wq3);
    conv3_mfma<<<B_ * 12, 256, 0, stream>>>(out + OUT_SPK2, wq3, recon3,
                                            bn3s, bn3b, bn3m, bn3v, xbuf);
    alif<<<(B_ * 128) / 256, 256, 0, stream>>>(xbuf, out + OUT_SPK3);
    // Readout
    readout<<<B_, 256, 0, stream>>>(out + OUT_SPK3, dw, db, a1w, a1b, a2w, a2b, out);
}

// Round 12
// 567.065 us; speedup vs baseline: 24.8895x; 1.3003x over previous
//
#include <hip/hip_runtime.h>
#include <cmath>

#define B_ 128
#define T_ 480
#define BT_ 61440

// output layout (fp32 elements)
#define OUT_SPK1 512
#define OUT_SPK2 3932672
#define OUT_SPK3 11796992

typedef __attribute__((ext_vector_type(4))) int i32x4;

__device__ __forceinline__ double softplus_d(double x) {
    return (x > 0.0) ? (x + log1p(exp(-x))) : log1p(exp(x));
}
__device__ __forceinline__ double sigmoid_d(double x) {
    return 1.0 / (1.0 + exp(-x));
}

// ---------------------------------------------------------------------------
// Kernel 1: conv1 (61440x64 @ 64x64) + bn1 -> xbuf (f64).
// ---------------------------------------------------------------------------
__global__ __launch_bounds__(256)
void conv1_bn(const float* __restrict__ x, const float* __restrict__ w1,
              const float* __restrict__ sc, const float* __restrict__ bi,
              const float* __restrict__ mn, const float* __restrict__ vr,
              double* __restrict__ xo)
{
    __shared__ float wl[64 * 64];
    __shared__ float xl[4 * 64];
    int tid = threadIdx.x;
#pragma unroll
    for (int i = 0; i < 16; i++) wl[tid + 256 * i] = w1[tid + 256 * i];
    int row0 = blockIdx.x * 4;
    xl[tid] = x[(size_t)row0 * 64 + tid];
    __syncthreads();
    int o = tid & 63, r = tid >> 6;
    double acc = 0.0;
#pragma unroll
    for (int w = 0; w < 64; w++)
        acc = fma((double)xl[r * 64 + w], (double)wl[w * 64 + o], acc);
    double y = (acc - (double)mn[o]) * (1.0 / sqrt((double)vr[o] + 1e-5)) * (double)sc[o]
             + (double)bi[o];
    xo[(size_t)(row0 + r) * 64 + o] = y;
}

// ---------------------------------------------------------------------------
// Kernel 2/4: HLIF scan over T per (b,c). Reads f64 xbuf.
// ---------------------------------------------------------------------------
__global__ void hlif(const double* __restrict__ xin, float* __restrict__ spk,
                     const float* __restrict__ vth_raw, const float* __restrict__ dec_raw,
                     int C)
{
    int idx = blockIdx.x * blockDim.x + threadIdx.x;
    int b = idx / C, c = idx - b * C;
    double vth = softplus_d((double)vth_raw[c]) + 0.5;
    double dec = sigmoid_d((double)dec_raw[c] + 2.0);
    dec = fmin(fmax(dec, 0.0), 0.99);
    const double* xp = xin + (size_t)b * T_ * C + c;
    float* sp = spk + (size_t)b * T_ * C + c;
    double v = 0.0;
    for (int t = 0; t < T_; t += 8) {
        double xv[8];
#pragma unroll
        for (int u = 0; u < 8; u++) xv[u] = xp[(size_t)(t + u) * C];
#pragma unroll
        for (int u = 0; u < 8; u++) {
            v = v * dec + xv[u];
            double s = (v - vth > 0.0) ? 1.0 : 0.0;
            v -= s * vth;
            sp[(size_t)(t + u) * C] = (float)s;
        }
    }
}

// ---------------------------------------------------------------------------
// Kernel Pa (generic): per-output-channel max |w| -> scale exponents.
// recon[o] = 2^(e-30) (exact), qscale[o] = 2^(30-e). K = chan count.
// ---------------------------------------------------------------------------
__global__ __launch_bounds__(64)
void prep_scale(const float* __restrict__ w, int K, double* __restrict__ recon,
                double* __restrict__ qscale)
{
    __shared__ float red[64];
    int o = blockIdx.x, l = threadIdx.x;
    float mx = 0.0f;
    for (int i = l; i < K; i += 64)
        mx = fmaxf(mx, fabsf(w[(size_t)i * 128 + o]));
    red[l] = mx;
    __syncthreads();
    for (int s = 32; s > 0; s >>= 1) {
        if (l < s) red[l] = fmaxf(red[l], red[l + s]);
        __syncthreads();
    }
    if (l == 0) {
        float m = red[0];
        int e = (m > 0.0f) ? (ilogbf(m) + 1) : 0;
        recon[o]  = ldexp(1.0, e - 30);
        qscale[o] = ldexp(1.0, 30 - e);
    }
}

// ---------------------------------------------------------------------------
// Kernel Pb3: quantize w3 -> 4 signed-byte digit planes, i8-B-fragment order.
// grp = (k*2+cb)*8+nt; lane l: o = nt*16+(l&15), c = cb*64+(l>>4)*16+e.
// ---------------------------------------------------------------------------
__global__ __launch_bounds__(256)
void prep_quant3(const float* __restrict__ w3, const double* __restrict__ qscale,
                 char* __restrict__ wq)
{
    int id = blockIdx.x * 256 + threadIdx.x;   // 32768 total
    int l = id & 63;
    int grp = id >> 6;                         // 512 grps
    int nt = grp & 7;
    int kc = grp >> 3;
    int cb = kc & 1, k = kc >> 1;
    int o = nt * 16 + (l & 15);
    int c0 = cb * 64 + (l >> 4) * 16;
    double qs = qscale[o];

    unsigned int pw[4][4];
#pragma unroll
    for (int p = 0; p < 4; p++)
#pragma unroll
        for (int wi = 0; wi < 4; wi++) pw[p][wi] = 0u;

#pragma unroll
    for (int e = 0; e < 16; e++) {
        float w = w3[((size_t)k * 128 + c0 + e) * 128 + o];
        int q = __double2int_rn((double)w * qs);
        int d0 = (int)(signed char)(q & 0xff); q = (q - d0) >> 8;
        int d1 = (int)(signed char)(q & 0xff); q = (q - d1) >> 8;
        int d2 = (int)(signed char)(q & 0xff); q = (q - d2) >> 8;
        int d3 = q;
        int sh = (e & 3) * 8, wi = e >> 2;
        pw[0][wi] |= ((unsigned)d0 & 0xffu) << sh;
        pw[1][wi] |= ((unsigned)d1 & 0xffu) << sh;
        pw[2][wi] |= ((unsigned)d2 & 0xffu) << sh;
        pw[3][wi] |= ((unsigned)d3 & 0xffu) << sh;
    }
#pragma unroll
    for (int p = 0; p < 4; p++) {
        uint4* dst = (uint4*)(wq + (((size_t)grp * 4 + p) * 64 + l) * 16);
        uint4 v; v.x = pw[p][0]; v.y = pw[p][1]; v.z = pw[p][2]; v.w = pw[p][3];
        *dst = v;
    }
}

// ---------------------------------------------------------------------------
// Kernel Pb2: quantize w2 (32,64,128) -> digit planes, grp = k*8+nt (Cin=64 =
// one K=64 chunk): lane l: o = nt*16+(l&15), c = (l>>4)*16+e. 1 MB.
// ---------------------------------------------------------------------------
__global__ __launch_bounds__(256)
void prep_quant2(const float* __restrict__ w2, const double* __restrict__ qscale,
                 char* __restrict__ wq)
{
    int id = blockIdx.x * 256 + threadIdx.x;   // 16384 total
    int l = id & 63;
    int grp = id >> 6;                         // 256 grps
    int nt = grp & 7;
    int k = grp >> 3;
    int o = nt * 16 + (l & 15);
    int c0 = (l >> 4) * 16;
    double qs = qscale[o];

    unsigned int pw[4][4];
#pragma unroll
    for (int p = 0; p < 4; p++)
#pragma unroll
        for (int wi = 0; wi < 4; wi++) pw[p][wi] = 0u;

#pragma unroll
    for (int e = 0; e < 16; e++) {
        float w = w2[((size_t)k * 64 + c0 + e) * 128 + o];
        int q = __double2int_rn((double)w * qs);
        int d0 = (int)(signed char)(q & 0xff); q = (q - d0) >> 8;
        int d1 = (int)(signed char)(q & 0xff); q = (q - d1) >> 8;
        int d2 = (int)(signed char)(q & 0xff); q = (q - d2) >> 8;
        int d3 = q;
        int sh = (e & 3) * 8, wi = e >> 2;
        pw[0][wi] |= ((unsigned)d0 & 0xffu) << sh;
        pw[1][wi] |= ((unsigned)d1 & 0xffu) << sh;
        pw[2][wi] |= ((unsigned)d2 & 0xffu) << sh;
        pw[3][wi] |= ((unsigned)d3 & 0xffu) << sh;
    }
#pragma unroll
    for (int p = 0; p < 4; p++) {
        uint4* dst = (uint4*)(wq + (((size_t)grp * 4 + p) * 64 + l) * 16);
        uint4 v; v.x = pw[p][0]; v.y = pw[p][1]; v.z = pw[p][2]; v.w = pw[p][3];
        *dst = v;
    }
}

// ---------------------------------------------------------------------------
// Kernel 3: conv2 via EXACT i8 MFMA (round-11 passing version, unchanged).
// ---------------------------------------------------------------------------
__global__ __launch_bounds__(512)
void conv2_mfma(const float* __restrict__ spk1, const char* __restrict__ wq,
                const double* __restrict__ recon,
                const float* __restrict__ sc, const float* __restrict__ bi,
                const float* __restrict__ mn, const float* __restrict__ vr,
                double* __restrict__ xo)
{
    __shared__ __align__(16) char S[160 * 80];   // 12.8 KB
    int tid = threadIdx.x;
    int jj = blockIdx.x;                 // 512 = 8 xcd * (16 b * 4 rho)
    int xcd = jj & 7, slot = jj >> 3;    // slot in [0,64)
    int bb = xcd + 8 * (slot >> 2);
    int rho = slot & 3;
    int rhop = (rho + 2) & 3;
    int m0 = (rho < 2) ? -16 : -15;
    const float* sb = spk1 + (size_t)bb * T_ * 64;

    for (int i = tid; i < 160 * 64; i += 512) {
        int widx = i >> 6, c = i & 63;
        int m = widx + m0;
        float v = ((unsigned)m < 120u) ? sb[(size_t)(4 * m + rhop) * 64 + c] : 0.0f;
        S[widx * 80 + c] = (char)v;
    }
    __syncthreads();

    int l = tid & 63, wv = tid >> 6;
    int wm = wv >> 2, wn = wv & 3;       // M-half, N-quarter
    int lm = l & 15, lg = l >> 4;

    i32x4 acc[4][2][4];
#pragma unroll
    for (int mt = 0; mt < 4; mt++)
#pragma unroll
        for (int nt = 0; nt < 2; nt++)
#pragma unroll
            for (int p = 0; p < 4; p++) acc[mt][nt][p] = (i32x4)(0);

    const char* arow0 = S + (wm * 64 + lm) * 80 + lg * 16;
    for (int k = 0; k < 32; k++) {
        const char* ap = arow0 + k * 80;
        i32x4 A0 = *(const i32x4*)(ap);
        i32x4 A1 = *(const i32x4*)(ap + 16 * 80);
        i32x4 A2 = *(const i32x4*)(ap + 32 * 80);
        i32x4 A3 = *(const i32x4*)(ap + 48 * 80);
        const char* bp = wq + (((size_t)(k * 8 + wn * 2) * 4) * 64 + l) * 16;
#pragma unroll
        for (int p = 0; p < 4; p++) {
            i32x4 B0 = *(const i32x4*)(bp + p * 1024);
            i32x4 B1 = *(const i32x4*)(bp + 4096 + p * 1024);
            acc[0][0][p] = __builtin_amdgcn_mfma_i32_16x16x64_i8(A0, B0, acc[0][0][p], 0, 0, 0);
            acc[1][0][p] = __builtin_amdgcn_mfma_i32_16x16x64_i8(A1, B0, acc[1][0][p], 0, 0, 0);
            acc[2][0][p] = __builtin_amdgcn_mfma_i32_16x16x64_i8(A2, B0, acc[2][0][p], 0, 0, 0);
            acc[3][0][p] = __builtin_amdgcn_mfma_i32_16x16x64_i8(A3, B0, acc[3][0][p], 0, 0, 0);
            acc[0][1][p] = __builtin_amdgcn_mfma_i32_16x16x64_i8(A0, B1, acc[0][1][p], 0, 0, 0);
            acc[1][1][p] = __builtin_amdgcn_mfma_i32_16x16x64_i8(A1, B1, acc[1][1][p], 0, 0, 0);
            acc[2][1][p] = __builtin_amdgcn_mfma_i32_16x16x64_i8(A2, B1, acc[2][1][p], 0, 0, 0);
            acc[3][1][p] = __builtin_amdgcn_mfma_i32_16x16x64_i8(A3, B1, acc[3][1][p], 0, 0, 0);
        }
    }

#pragma unroll
    for (int nt = 0; nt < 2; nt++) {
        int o = (wn * 2 + nt) * 16 + lm;
        double rc = recon[o];
        double m_ = (double)mn[o], rs_ = 1.0 / sqrt((double)vr[o] + 1e-5);
        double s_ = (double)sc[o], b_ = (double)bi[o];
#pragma unroll
        for (int mt = 0; mt < 4; mt++)
#pragma unroll
            for (int rg = 0; rg < 4; rg++) {
                int a = (wm * 4 + mt) * 16 + lg * 4 + rg;
                if (a < 120) {
                    long long D = (long long)acc[mt][nt][0][rg]
                                + ((long long)acc[mt][nt][1][rg] << 8)
                                + ((long long)acc[mt][nt][2][rg] << 16)
                                + ((long long)acc[mt][nt][3][rg] << 24);
                    double val = (double)D * rc;
                    int t_out = 4 * a + rho;
                    xo[((size_t)bb * T_ + t_out) * 128 + o] =
                        (val - m_) * rs_ * s_ + b_;
                }
            }
    }
}

// ---------------------------------------------------------------------------
// Kernel 5: conv3 via EXACT i8 MFMA — TLP restructure: 8 waves x nt=1 (acc
// halves to 48 VGPR -> 4 waves/SIMD ceiling, 16 resident waves/CU) + register
// double-buffer on B fragments (prefetch kc+1 while MFMAing kc). Integer
// accumulation is order-exact -> bitwise-identical results to round 10/11.
// ---------------------------------------------------------------------------
__global__ __launch_bounds__(512)
void conv3_mfma(const float* __restrict__ spk2, const char* __restrict__ wq,
                const double* __restrict__ recon,
                const float* __restrict__ sc, const float* __restrict__ bi,
                const float* __restrict__ mn, const float* __restrict__ vr,
                double* __restrict__ xo)
{
    __shared__ __align__(16) char S[80 * 144];   // 11.25 KB
    int tid = threadIdx.x;
    int jj = blockIdx.x;               // grid 1536 = 8 xcd * (16 b * 12 rho)
    int xcd = jj & 7, slot = jj >> 3;
    int bb = xcd + 8 * (slot / 12);
    int rho = slot % 12;
    int rhop = (rho < 6) ? rho + 6 : rho - 6;
    int koff = (rho < 6) ? 0 : 1;
    const float* sb = spk2 + (size_t)bb * T_ * 128;

    for (int i = tid; i < 80 * 128; i += 512) {
        int w = i >> 7, c = i & 127;
        float v = (w >= 16 && w < 56) ? sb[(size_t)(12 * (w - 16) + rhop) * 128 + c] : 0.0f;
        S[w * 144 + c] = (char)v;
    }
    __syncthreads();

    int l = tid & 63, wv = tid >> 6;   // wv 0..7 = output-channel tile (nt)
    int lm = l & 15, lg = l >> 4;
    const char* arow = S + (lm + koff) * 144 + lg * 16;
    // wq byte offset for (kc, plane p): kc*32768 + wv*4096 + p*1024 + l*16
    const char* bp0 = wq + (size_t)wv * 4096 + (size_t)l * 16;

    i32x4 acc[3][4];
#pragma unroll
    for (int mt = 0; mt < 3; mt++)
#pragma unroll
        for (int p = 0; p < 4; p++) acc[mt][p] = (i32x4)(0);

    i32x4 Bc[4], Bn[4];
#pragma unroll
    for (int p = 0; p < 4; p++) Bc[p] = *(const i32x4*)(bp0 + p * 1024);

    for (int kc = 0; kc < 64; kc++) {            // kc = k*2 + cb
        if (kc < 63) {
            const char* bpn = bp0 + (size_t)(kc + 1) * 32768;
#pragma unroll
            for (int p = 0; p < 4; p++) Bn[p] = *(const i32x4*)(bpn + p * 1024);
        }
        int k = kc >> 1, cb = kc & 1;
        const char* ap = arow + k * 144 + cb * 64;
        i32x4 A0 = *(const i32x4*)(ap);
        i32x4 A1 = *(const i32x4*)(ap + 16 * 144);
        i32x4 A2 = *(const i32x4*)(ap + 32 * 144);
#pragma unroll
        for (int p = 0; p < 4; p++) {
            acc[0][p] = __builtin_amdgcn_mfma_i32_16x16x64_i8(A0, Bc[p], acc[0][p], 0, 0, 0);
            acc[1][p] = __builtin_amdgcn_mfma_i32_16x16x64_i8(A1, Bc[p], acc[1][p], 0, 0, 0);
            acc[2][p] = __builtin_amdgcn_mfma_i32_16x16x64_i8(A2, Bc[p], acc[2][p], 0, 0, 0);
        }
#pragma unroll
        for (int p = 0; p < 4; p++) Bc[p] = Bn[p];
    }

    int o = wv * 16 + lm;
    double rc = recon[o];
    double m_ = (double)mn[o], rs_ = 1.0 / sqrt((double)vr[o] + 1e-5);
    double s_ = (double)sc[o], b_ = (double)bi[o];
#pragma unroll
    for (int mt = 0; mt < 3; mt++)
#pragma unroll
        for (int rg = 0; rg < 4; rg++) {
            int mo = mt * 16 + lg * 4 + rg;
            if (mo < 40) {
                long long D = (long long)acc[mt][0][rg]
                            + ((long long)acc[mt][1][rg] << 8)
                            + ((long long)acc[mt][2][rg] << 16)
                            + ((long long)acc[mt][3][rg] << 24);
                double val = (double)D * rc;
                int t_out = 12 * mo + rho;
                xo[((size_t)bb * T_ + t_out) * 128 + o] =
                    (val - m_) * rs_ * s_ + b_;
            }
        }
}

// ---------------------------------------------------------------------------
// Kernel 6: ALIF scan per (b,c), C=128. Reads f64 xbuf.
// ---------------------------------------------------------------------------
__global__ void alif(const double* __restrict__ xin, float* __restrict__ spk)
{
    int idx = blockIdx.x * blockDim.x + threadIdx.x;
    int b = idx >> 7, c = idx & 127;
    const double* xp = xin + (size_t)b * T_ * 128 + c;
    float* sp = spk + (size_t)b * T_ * 128 + c;
    double v = 0.0, th = 0.0, ps = 0.0;
    const double dd = 0.9, adp = 0.9, beta = 1.8;
    for (int t = 0; t < T_; t += 8) {
        double xv[8];
#pragma unroll
        for (int u = 0; u < 8; u++) xv[u] = xp[(size_t)(t + u) * 128];
#pragma unroll
        for (int u = 0; u < 8; u++) {
            th = th * adp + ps * beta;
            v = v * dd + xv[u];
            double vth = 0.5 + th;
            double s = (v - vth > 0.0) ? 1.0 : 0.0;
            v -= s * vth;
            ps = s;
            sp[(size_t)(t + u) * 128] = (float)s;
        }
    }
}

// ---------------------------------------------------------------------------
// Kernel 7: readout — dense + LI scan + dp + attention + logits. 1 block per b.
// ---------------------------------------------------------------------------
__global__ __launch_bounds__(256)
void readout(const float* __restrict__ spk3, const float* __restrict__ dw,
             const float* __restrict__ db, const float* __restrict__ a1w,
             const float* __restrict__ a1b, const float* __restrict__ a2w,
             const float* __restrict__ a2b, float* __restrict__ out)
{
    __shared__ double dl[480 * 4];
    __shared__ double dp[20 * 4];
    __shared__ double zl[20];
    __shared__ double red[1];
    int b = blockIdx.x, tid = threadIdx.x;
    const float* sp = spk3 + (size_t)b * T_ * 128;

    for (int i = tid; i < 1920; i += 256) {
        int t = i >> 2, j = i & 3;
        const float* row = sp + (size_t)t * 128;
        double acc = 0.0;
        for (int c = 0; c < 128; c++)
            acc = fma((double)row[c], (double)dw[c * 4 + j], acc);
        dl[i] = acc + (double)db[j];
    }
    __syncthreads();
    if (tid < 4) {
        const double dec = 0.9, om = 1.0 - 0.9;
        double v = 0.0;
        for (int t = 0; t < T_; t++) {
            v = v * dec + dl[t * 4 + tid] * om;
            dl[t * 4 + tid] = v;
        }
    }
    __syncthreads();
    if (tid < 80) {
        int g = tid >> 2, j = tid & 3;
        double s1 = 0.0, s2 = 0.0;
        for (int u = 0; u < 12; u++) {
            s1 += dl[(g * 24 + u) * 4 + j];
            s2 += dl[(g * 24 + 12 + u) * 4 + j];
        }
        dp[g * 4 + j] = s2 / 12.0 - s1 / 12.0;
    }
    __syncthreads();
    if (tid < 20) {
        int g = tid;
        double z = (double)a2b[0];
        for (int i = 0; i < 8; i++) {
            double h = (double)a1b[i];
            for (int j = 0; j < 4; j++)
                h = fma(dp[g * 4 + j], (double)a1w[j * 8 + i], h);
            h = fmax(h, 0.0);
            z = fma(h, (double)a2w[i], z);
        }
        zl[g] = z;
    }
    __syncthreads();
    if (tid == 0) {
        double m = zl[0];
        for (int g = 1; g < 20; g++) m = fmax(m, zl[g]);
        double s = 0.0;
        for (int g = 0; g < 20; g++) { zl[g] = exp(zl[g] - m); s += zl[g]; }
        red[0] = s;
    }
    __syncthreads();
    if (tid < 4) {
        double s = red[0];
        double acc = 0.0;
        for (int g = 0; g < 20; g++) acc += dp[g * 4 + tid] * (zl[g] / s);
        out[b * 4 + tid] = (float)acc;
    }
}

// ---------------------------------------------------------------------------
extern "C" void kernel_launch(void* const* d_in, const int* in_sizes, int n_in,
                              void* d_out, int out_size, void* d_ws, size_t ws_size,
                              hipStream_t stream)
{
    const float* x     = (const float*)d_in[0];
    const float* w1    = (const float*)d_in[1];
    const float* bn1s  = (const float*)d_in[2];
    const float* bn1b  = (const float*)d_in[3];
    const float* bn1m  = (const float*)d_in[4];
    const float* bn1v  = (const float*)d_in[5];
    const float* vth1  = (const float*)d_in[6];
    const float* dec1  = (const float*)d_in[7];
    const float* w2    = (const float*)d_in[8];
    const float* bn2s  = (const float*)d_in[9];
    const float* bn2b  = (const float*)d_in[10];
    const float* bn2m  = (const float*)d_in[11];
    const float* bn2v  = (const float*)d_in[12];
    const float* vth2  = (const float*)d_in[13];
    const float* dec2  = (const float*)d_in[14];
    const float* w3    = (const float*)d_in[15];
    const float* bn3s  = (const float*)d_in[16];
    const float* bn3b  = (const float*)d_in[17];
    const float* bn3m  = (const float*)d_in[18];
    const float* bn3v  = (const float*)d_in[19];
    const float* dw    = (const float*)d_in[20];
    const float* db    = (const float*)d_in[21];
    const float* a1w   = (const float*)d_in[22];
    const float* a1b   = (const float*)d_in[23];
    const float* a2w   = (const float*)d_in[24];
    const float* a2b   = (const float*)d_in[25];

    float* out = (float*)d_out;
    double* xbuf = (double*)d_ws;                         // 61440*128 doubles = 62.9 MB

    // Staging in the spk3 output slot (31.5 MB): consumed before alif
    // overwrites it (stream-ordered).
    char*   base    = (char*)(out + OUT_SPK3);
    char*   wq3     = base;                               // 2 MB
    double* recon3  = (double*)(base + 0x200000);         // 128 d
    double* qscale3 = recon3 + 128;
    char*   wq2     = base + 0x200000 + 0x1000;           // 1 MB
    double* recon2  = (double*)(base + 0x300000 + 0x1000);
    double* qscale2 = recon2 + 128;

    // Stage 1
    conv1_bn<<<BT_ / 4, 256, 0, stream>>>(x, w1, bn1s, bn1b, bn1m, bn1v, xbuf);
    hlif<<<(B_ * 64) / 256, 256, 0, stream>>>(xbuf, out + OUT_SPK1, vth1, dec1, 64);
    // Stage 2: exact i8 fixed-point MFMA
    prep_scale<<<128, 64, 0, stream>>>(w2, 2048, recon2, qscale2);
    prep_quant2<<<64, 256, 0, stream>>>(w2, qscale2, wq2);
    conv2_mfma<<<B_ * 4, 512, 0, stream>>>(out + OUT_SPK1, wq2, recon2,
                                           bn2s, bn2b, bn2m, bn2v, xbuf);
    hlif<<<(B_ * 128) / 256, 256, 0, stream>>>(xbuf, out + OUT_SPK2, vth2, dec2, 128);
    // Stage 3: exact i8 fixed-point MFMA
    prep_scale<<<128, 64, 0, stream>>>(w3, 4096, recon3, qscale3);
    prep_quant3<<<128, 256, 0, stream>>>(w3, qscale3, wq3);
    conv3_mfma<<<B_ * 12, 512, 0, stream>>>(out + OUT_SPK2, wq3, recon3,
                                            bn3s, bn3b, bn3m, bn3v, xbuf);
    alif<<<(B_ * 128) / 256, 256, 0, stream>>>(xbuf, out + OUT_SPK3);
    // Readout
    readout<<<B_, 256, 0, stream>>>(out + OUT_SPK3, dw, db, a1w, a1b, a2w, a2b, out);
}